// Round 11
// baseline (175.723 us; speedup 1.0000x reference)
//
#include <hip/hip_runtime.h>
#include <math.h>

// Problem constants
#define SEQ   2048
#define NROWS 8192   // B*N

typedef unsigned short ushort_t;
typedef __attribute__((ext_vector_type(8))) short bf16x8;
typedef __attribute__((ext_vector_type(4))) float f32x4;

// Workspace offsets (ushort units)
#define U_EXPR   0ull            // 8192*512
#define U_A192   4194304ull      // 8192*192  ([te1|tp])
#define U_H      5767168ull      // 8192*512
#define U_QKV    9961472ull      // 8192*1544
#define U_KN     26804224ull     // 8192*512
#define U_VT     30998528ull     // 32*64*2048
#define U_AO     35192832ull     // 8192*512
#define U_W1T    39387136ull     // 64*512
#define U_W2RAW  39419904ull     // 64*512
#define U_CATWT  39452672ull     // 512*768
#define U_QKVWT  39845888ull     // 1544*512
#define U_HEWT   40898560ull     // 512*512
#define U_WPRIME 41160704ull     // 512*192
#define U_WOHE   41259008ull     // 512*512
#define U_F32    41521152ull     // fp32 region (8192 floats)
#define U_ORAW   41537536ull     // 512*512 bf16, o_w native layout

// fp32 region layout (float offsets)
#define F_TDT    0
#define F_QKVB   512
#define F_BIASH  2056    // [4][512]
#define F_BIASEO 4104    // [512]
#define F_BIASPO 4616    // [4]
#define F_WHP    4620    // [512][3]

// d_out offsets (floats): (expr_out, pos_out, tdt)
#define DOUT_EXPR 0ull
#define DOUT_POS  4194304ull
#define DOUT_TDT  4218880ull

#define LOG2E 1.44269504088896340736f

static __device__ __forceinline__ ushort_t f2bf(float f) {
    union { float f; unsigned int u; } v; v.f = f;
    unsigned int r = (v.u + 0x7fffu + ((v.u >> 16) & 1u)) >> 16;
    return (ushort_t)r;
}
static __device__ __forceinline__ float bf2f(ushort_t u) {
    union { unsigned int u; float f; } v; v.u = ((unsigned int)u) << 16;
    return v.f;
}

// async global->LDS, 16B per lane; LDS dest = wave-uniform base + lane*16
static __device__ __forceinline__ void gload16(const void* g, void* l) {
    __builtin_amdgcn_global_load_lds(
        (const __attribute__((address_space(1))) void*)g,
        (__attribute__((address_space(3))) void*)l,
        16, 0, 0);
}

// ---------------------------------------------------------------------------
// Weight prep: mode 0 = transpose 64x64 tile (src[K][N] -> dst[n*dstStride+k]),
// mode 1 = convert-copy 16384-elem tile. Blocks >= 658: qkv bias gather.
// ---------------------------------------------------------------------------
struct WtSeg { const float* src; ushort_t* dst; int K, N, tK, tile0, dstStride, mode; };
struct WtTable { WtSeg s[10]; };

__global__ __launch_bounds__(256) void wt_transpose(
    WtTable tab, const float* __restrict__ qb, const float* __restrict__ kb,
    const float* __restrict__ vb, float* __restrict__ bias_dst)
{
    const int bid = blockIdx.x;
    const int tid = threadIdx.x;
    if (bid >= 658) {
        int t = (bid - 658) * 256 + tid;
        if (t < 520) bias_dst[t] = qb[t];
        else if (t < 1032) bias_dst[t] = kb[t - 520];
        else if (t < 1544) bias_dst[t] = vb[t - 1032];
        return;
    }
    int si = 0;
#pragma unroll
    for (int i = 1; i < 10; ++i)
        if (bid >= tab.s[i].tile0) si = i;
    const WtSeg sg = tab.s[si];
    const int local = bid - sg.tile0;

    if (sg.mode == 1) {
        long base = (long)local * 16384;
#pragma unroll
        for (int i = 0; i < 8; ++i) {
            long p = base + i * 2048 + tid * 8;
            float4 a = *(const float4*)&sg.src[p];
            float4 b = *(const float4*)&sg.src[p + 4];
            bf16x8 o;
            o[0] = (short)f2bf(a.x); o[1] = (short)f2bf(a.y);
            o[2] = (short)f2bf(a.z); o[3] = (short)f2bf(a.w);
            o[4] = (short)f2bf(b.x); o[5] = (short)f2bf(b.y);
            o[6] = (short)f2bf(b.z); o[7] = (short)f2bf(b.w);
            *(bf16x8*)&sg.dst[p] = o;
        }
        return;
    }

    __shared__ float t[64][65];
    const int k0 = (local % sg.tK) * 64;
    const int n0 = (local / sg.tK) * 64;
#pragma unroll
    for (int i = 0; i < 16; ++i) {
        int e = tid + i * 256;
        int r = e >> 6, c = e & 63;
        float v = 0.f;
        if (k0 + r < sg.K && n0 + c < sg.N)
            v = sg.src[(long)(k0 + r) * sg.N + n0 + c];
        t[r][c] = v;
    }
    __syncthreads();
#pragma unroll
    for (int i = 0; i < 16; ++i) {
        int e = tid + i * 256;
        int rn = e >> 6, ck = e & 63;
        if (n0 + rn < sg.N && k0 + ck < sg.K)
            sg.dst[(long)(n0 + rn) * sg.dstStride + k0 + ck] = f2bf(t[ck][rn]);
    }
}

// ---------------------------------------------------------------------------
// Bias folding (wave-per-output) — unchanged.
// ---------------------------------------------------------------------------
__global__ __launch_bounds__(256) void biasfold_kernel(
    const ushort_t* __restrict__ catwt, const ushort_t* __restrict__ hewt,
    const float* __restrict__ expr_b2, const float* __restrict__ tdt,
    const float* __restrict__ cat_b, const float* __restrict__ o_b,
    const float* __restrict__ he_b, const float* __restrict__ o_w,
    const float* __restrict__ hp_w, const float* __restrict__ hp_b,
    float* __restrict__ bias_h, float* __restrict__ bias_eo,
    float* __restrict__ whp, float* __restrict__ bias_po)
{
    const int wid = blockIdx.x * 4 + (threadIdx.x >> 6);
    const int lane = threadIdx.x & 63;
    float s = 0.f;
    if (wid < 2048) {
        int b = wid >> 9, n = wid & 511;
        bf16x8 wv = *(const bf16x8*)&catwt[(long)n * 768 + lane * 8];
        float4 e0 = *(const float4*)&expr_b2[lane * 8];
        float4 e1 = *(const float4*)&expr_b2[lane * 8 + 4];
        s = bf2f((ushort_t)wv[0]) * e0.x + bf2f((ushort_t)wv[1]) * e0.y +
            bf2f((ushort_t)wv[2]) * e0.z + bf2f((ushort_t)wv[3]) * e0.w +
            bf2f((ushort_t)wv[4]) * e1.x + bf2f((ushort_t)wv[5]) * e1.y +
            bf2f((ushort_t)wv[6]) * e1.z + bf2f((ushort_t)wv[7]) * e1.w;
        float2 tt = *(const float2*)&tdt[b * 128 + lane * 2];
        s += bf2f(catwt[(long)n * 768 + 512 + lane * 2]) * tt.x;
        s += bf2f(catwt[(long)n * 768 + 513 + lane * 2]) * tt.y;
#pragma unroll
        for (int o = 32; o >= 1; o >>= 1) s += __shfl_xor(s, o);
        if (lane == 0) bias_h[b * 512 + n] = s + cat_b[n];
    } else if (wid < 2560) {
        int n = wid - 2048;
        bf16x8 wv = *(const bf16x8*)&hewt[(long)n * 512 + lane * 8];
        float4 e0 = *(const float4*)&o_b[lane * 8];
        float4 e1 = *(const float4*)&o_b[lane * 8 + 4];
        s = bf2f((ushort_t)wv[0]) * e0.x + bf2f((ushort_t)wv[1]) * e0.y +
            bf2f((ushort_t)wv[2]) * e0.z + bf2f((ushort_t)wv[3]) * e0.w +
            bf2f((ushort_t)wv[4]) * e1.x + bf2f((ushort_t)wv[5]) * e1.y +
            bf2f((ushort_t)wv[6]) * e1.z + bf2f((ushort_t)wv[7]) * e1.w;
#pragma unroll
        for (int o = 32; o >= 1; o >>= 1) s += __shfl_xor(s, o);
        if (lane == 0) bias_eo[n] = s + he_b[n];
    } else if (wid < 4096) {
        int t = wid - 2560;
        int c = t >> 9, k = t & 511;
#pragma unroll
        for (int i = 0; i < 8; ++i) {
            int j = i * 64 + lane;
            s = fmaf(o_w[(long)k * 512 + j], hp_w[j * 3 + c], s);
        }
#pragma unroll
        for (int o = 32; o >= 1; o >>= 1) s += __shfl_xor(s, o);
        if (lane == 0) whp[k * 3 + c] = s;
    } else if (wid < 4099) {
        int c = wid - 4096;
#pragma unroll
        for (int i = 0; i < 8; ++i) {
            int j = i * 64 + lane;
            s = fmaf(o_b[j], hp_w[j * 3 + c], s);
        }
#pragma unroll
        for (int o = 32; o >= 1; o >>= 1) s += __shfl_xor(s, o);
        if (lane == 0) bias_po[c] = s + hp_b[c];
    }
}

// ---------------------------------------------------------------------------
// bf16 MFMA GEMM — unchanged (global_load_lds, swizzled source).
// ---------------------------------------------------------------------------
template <int RELU, int OUT_BF16, int HASBIAS, int BBSTRIDE>
__global__ __launch_bounds__(512) void hgemm(
    const ushort_t* __restrict__ A, int lda,
    const ushort_t* __restrict__ Wt, int ldw,
    const float* __restrict__ bias,
    void* __restrict__ Cv, int ldc,
    int N, int K)
{
    __shared__ __align__(16) ushort_t As[128 * 64];
    __shared__ __align__(16) ushort_t Bs[128 * 64];

    const int tid = threadIdx.x;
    const int lane = tid & 63, w = tid >> 6;
    const int lo = lane & 15, hi = lane >> 4;
    const int wm = w >> 2, wn = w & 3;
    const long m0 = (long)blockIdx.y * 128;
    const int n0 = blockIdx.x * 128;

    f32x4 acc[4][2];
#pragma unroll
    for (int mt = 0; mt < 4; ++mt)
#pragma unroll
        for (int nt = 0; nt < 2; ++nt) acc[mt][nt] = (f32x4)0.f;

    for (int kt = 0; kt < K; kt += 64) {
#pragma unroll
        for (int i = 0; i < 2; ++i) {
            int c = w * 128 + i * 64 + lane;
            int r = c >> 3, ch = c & 7;
            int sch = ch ^ (r & 7);
            gload16(&A[(m0 + r) * (long)lda + kt + sch * 8],
                    &As[(w * 128 + i * 64) * 8]);
            gload16(&Wt[(long)(n0 + r) * ldw + kt + sch * 8],
                    &Bs[(w * 128 + i * 64) * 8]);
        }
        __syncthreads();

#pragma unroll
        for (int ks = 0; ks < 2; ++ks) {
            bf16x8 af[4], bfr[2];
#pragma unroll
            for (int mt = 0; mt < 4; ++mt) {
                int m = wm * 64 + mt * 16 + lo;
                af[mt] = *(const bf16x8*)&As[m * 64 + (((ks * 4 + hi) ^ (lo & 7)) * 8)];
            }
#pragma unroll
            for (int nt = 0; nt < 2; ++nt) {
                int n = wn * 32 + nt * 16 + lo;
                bfr[nt] = *(const bf16x8*)&Bs[n * 64 + (((ks * 4 + hi) ^ (lo & 7)) * 8)];
            }
#pragma unroll
            for (int mt = 0; mt < 4; ++mt)
#pragma unroll
                for (int nt = 0; nt < 2; ++nt)
                    acc[mt][nt] = __builtin_amdgcn_mfma_f32_16x16x32_bf16(
                        af[mt], bfr[nt], acc[mt][nt], 0, 0, 0);
        }
        __syncthreads();
    }

#pragma unroll
    for (int mt = 0; mt < 4; ++mt)
#pragma unroll
        for (int nt = 0; nt < 2; ++nt) {
            int col = n0 + wn * 32 + nt * 16 + lo;
            if (col < N) {
                float bv = 0.f;
                if (HASBIAS)
                    bv = BBSTRIDE ? bias[(int)(m0 >> 11) * BBSTRIDE + col] : bias[col];
#pragma unroll
                for (int r = 0; r < 4; ++r) {
                    long row = m0 + wm * 64 + mt * 16 + hi * 4 + r;
                    float v = acc[mt][nt][r] + bv;
                    if (RELU) v = fmaxf(v, 0.f);
                    if (OUT_BF16) ((ushort_t*)Cv)[row * (long)ldc + col] = f2bf(v);
                    else          ((float*)Cv)[row * (long)ldc + col] = v;
                }
            }
        }
}

// ---------------------------------------------------------------------------
// Position MLP -> a192[:, 64:192] (bf16) — unchanged from round 10.
// ---------------------------------------------------------------------------
__global__ __launch_bounds__(256) void posmlp_kernel(
    const float* __restrict__ pos,
    const float* __restrict__ w1, const float* __restrict__ b1,
    const float* __restrict__ w2, const float* __restrict__ b2,
    ushort_t* __restrict__ a192)
{
    __shared__ __align__(16) float w1s[256];
    __shared__ __align__(16) float b1s[64];
    __shared__ __align__(16) float w2t[128 * 72];
    __shared__ __align__(16) float b2s[128];

    const int tid = threadIdx.x;
    w1s[tid] = w1[tid];
    if (tid < 64) b1s[tid] = b1[tid];
    if (tid < 128) b2s[tid] = b2[tid];
    for (int i = tid; i < 8192; i += 256) {
        int k = i >> 7, o = i & 127;
        w2t[o * 72 + k] = w2[i];
    }
    __syncthreads();

    const long r = (long)blockIdx.x * 32 + (tid >> 3);
    const int chunk = tid & 7;
    float px = pos[r * 3 + 0], py = pos[r * 3 + 1], pz = pos[r * 3 + 2];
    float nrm = sqrtf(px * px + py * py + pz * pz);
    float inv = 1.f / (nrm + 1e-7f);
    float pf0 = px * inv, pf1 = py * inv, pf2 = pz * inv, pf3 = nrm;

    float h1[64];
#pragma unroll
    for (int o = 0; o < 64; ++o) {
        float a = b1s[o];
        a = fmaf(pf0, w1s[o], a);
        a = fmaf(pf1, w1s[64 + o], a);
        a = fmaf(pf2, w1s[128 + o], a);
        a = fmaf(pf3, w1s[192 + o], a);
        h1[o] = fmaxf(a, 0.f);
    }
    ushort_t* dst = &a192[r * 192 + 64];
#pragma unroll
    for (int j = 0; j < 16; ++j) {
        int o = chunk + 8 * j;
        float s = b2s[o];
#pragma unroll
        for (int i4 = 0; i4 < 16; ++i4) {
            float4 wv = *(const float4*)&w2t[o * 72 + i4 * 4];
            s = fmaf(h1[i4 * 4 + 0], wv.x, s);
            s = fmaf(h1[i4 * 4 + 1], wv.y, s);
            s = fmaf(h1[i4 * 4 + 2], wv.z, s);
            s = fmaf(h1[i4 * 4 + 3], wv.w, s);
        }
        dst[o] = f2bf(s);
    }
}

// tdt = diffusion_time @ yy_w + yy_b (fp32, exact)
__global__ __launch_bounds__(512) void tdt_kernel(
    const float* __restrict__ dt, const float* __restrict__ yyw,
    const float* __restrict__ yyb, float* __restrict__ tdt_ws,
    float* __restrict__ out_tail)
{
    const int t = threadIdx.x;
    const int b = t >> 7, o = t & 127;
    float s = yyb[o];
    for (int k = 0; k < 128; ++k) s = fmaf(dt[b * 128 + k], yyw[k * 128 + o], s);
    tdt_ws[t] = s;
    out_tail[t] = s;
}

// ---------------------------------------------------------------------------
// qkv postprocess: K rmsnorm + V transpose — unchanged.
// ---------------------------------------------------------------------------
__global__ __launch_bounds__(256) void qkvpost_kernel(
    const ushort_t* __restrict__ qkv, const float* __restrict__ knw,
    ushort_t* __restrict__ kn, ushort_t* __restrict__ Vt)
{
    __shared__ ushort_t t[64][72];
    __shared__ float knw_s[64];
    const int bh = blockIdx.x, b = bh >> 3, h = bh & 7;
    const int n0 = blockIdx.y * 64;
    const int tid = threadIdx.x;
    if (tid < 64) knw_s[tid] = knw[tid];
#pragma unroll
    for (int i = 0; i < 2; ++i) {
        int c = tid + i * 256;
        int r = c >> 3, ch = c & 7;
        *(bf16x8*)&t[r][ch * 8] =
            *(const bf16x8*)&qkv[(long)(b * SEQ + n0 + r) * 1544 + 1032 + h * 64 + ch * 8];
    }
    __syncthreads();
#pragma unroll
    for (int i = 0; i < 2; ++i) {
        int c = tid + i * 256;
        int r = c >> 3, ch = c & 7;
        bf16x8 kv = *(const bf16x8*)&qkv[(long)(b * SEQ + n0 + r) * 1544 + 520 + h * 64 + ch * 8];
        float x[8], ss = 0.f;
#pragma unroll
        for (int j = 0; j < 8; ++j) { x[j] = bf2f((ushort_t)kv[j]); ss = fmaf(x[j], x[j], ss); }
        ss += __shfl_xor(ss, 1);
        ss += __shfl_xor(ss, 2);
        ss += __shfl_xor(ss, 4);
        float invr = rsqrtf(ss * (1.f / 64.f) + 1e-6f);
        bf16x8 o;
#pragma unroll
        for (int j = 0; j < 8; ++j) o[j] = (short)f2bf(x[j] * knw_s[ch * 8 + j] * invr);
        *(bf16x8*)&kn[(long)(b * SEQ + n0 + r) * 512 + h * 64 + ch * 8] = o;
    }
    const int d = tid >> 2;
#pragma unroll
    for (int i = 0; i < 2; ++i) {
        int cc = (tid & 3) * 2 + i;
        bf16x8 pk;
#pragma unroll
        for (int j = 0; j < 8; ++j) pk[j] = (short)t[cc * 8 + j][d];
        *(bf16x8*)&Vt[((long)(bh * 64 + d)) * SEQ + n0 + cc * 8] = pk;
    }
}

// ---------------------------------------------------------------------------
// Flash attention, bf16 MFMA 16x16x32.
// Occupancy restructure: 16 q-rows/wave, 64 q-rows/block, grid (32, 32) =
// 1024 blocks -> 4 blocks/CU x 4 waves = 4 waves/SIMD (was 2). LDS 40KB.
// Double-buffered K/V, 1 barrier/K-tile; inline Q rmsnorm; exp2-domain
// softmax via raw v_exp_f32; swapped QK^T; packed P writes.
// ---------------------------------------------------------------------------
__global__ __launch_bounds__(256) void flash_attn_mfma(
    const ushort_t* __restrict__ QKV, const ushort_t* __restrict__ Kn,
    const ushort_t* __restrict__ Vt, const float* __restrict__ qnw,
    ushort_t* __restrict__ AO)
{
    __shared__ __align__(16) ushort_t Ks[2][64 * 64];
    __shared__ __align__(16) ushort_t Vs[2][64 * 64];
    __shared__ __align__(16) ushort_t Ps[4][16 * 64];

    const int tid = threadIdx.x;
    const int lane = tid & 63;
    const int w = tid >> 6;
    const int lo = lane & 15, hi = lane >> 4;
    const int bh = blockIdx.x, b = bh >> 3, h = bh & 7;
    const int qb = blockIdx.y * 64 + w * 16;

    // ---- Q load + inline rmsnorm (row on lanes {lo, lo+16, lo+32, lo+48}) ----
    bf16x8 qfrag[2];
    {
        float qx[2][8], ss = 0.f;
#pragma unroll
        for (int ks = 0; ks < 2; ++ks) {
            bf16x8 q = *(const bf16x8*)&QKV[(long)(b * SEQ + qb + lo) * 1544 +
                                            h * 64 + ks * 32 + hi * 8];
#pragma unroll
            for (int j = 0; j < 8; ++j) {
                qx[ks][j] = bf2f((ushort_t)q[j]);
                ss = fmaf(qx[ks][j], qx[ks][j], ss);
            }
        }
        ss += __shfl_xor(ss, 16);
        ss += __shfl_xor(ss, 32);
        float invr = rsqrtf(ss * (1.f / 64.f) + 1e-6f) * (0.125f * LOG2E);
#pragma unroll
        for (int ks = 0; ks < 2; ++ks) {
            bf16x8 f;
#pragma unroll
            for (int j = 0; j < 8; ++j)
                f[j] = (short)f2bf(qx[ks][j] * qnw[ks * 32 + hi * 8 + j] * invr);
            qfrag[ks] = f;
        }
    }

    f32x4 accO[4];
#pragma unroll
    for (int nt = 0; nt < 4; ++nt) accO[nt] = (f32x4)0.f;
    float l_part = 0.f;

    const int sr0 = tid >> 3, sc0 = tid & 7;
    const int sr1 = (tid + 256) >> 3, sc1 = tid & 7;
    const int wo0 = sr0 * 64 + ((sc0 ^ (sr0 & 7)) * 8);
    const int wo1 = sr1 * 64 + ((sc1 ^ (sr1 & 7)) * 8);

    bf16x8 kreg0, kreg1, vreg0, vreg1;
    kreg0 = *(const bf16x8*)&Kn[(b * SEQ + sr0) * 512 + h * 64 + sc0 * 8];
    vreg0 = *(const bf16x8*)&Vt[((long)(bh * 64 + sr0)) * SEQ + sc0 * 8];
    kreg1 = *(const bf16x8*)&Kn[(b * SEQ + sr1) * 512 + h * 64 + sc1 * 8];
    vreg1 = *(const bf16x8*)&Vt[((long)(bh * 64 + sr1)) * SEQ + sc1 * 8];
    *(bf16x8*)&Ks[0][wo0] = kreg0;
    *(bf16x8*)&Vs[0][wo0] = vreg0;
    *(bf16x8*)&Ks[0][wo1] = kreg1;
    *(bf16x8*)&Vs[0][wo1] = vreg1;
    kreg0 = *(const bf16x8*)&Kn[(b * SEQ + 64 + sr0) * 512 + h * 64 + sc0 * 8];
    vreg0 = *(const bf16x8*)&Vt[((long)(bh * 64 + sr0)) * SEQ + 64 + sc0 * 8];
    kreg1 = *(const bf16x8*)&Kn[(b * SEQ + 64 + sr1) * 512 + h * 64 + sc1 * 8];
    vreg1 = *(const bf16x8*)&Vt[((long)(bh * 64 + sr1)) * SEQ + 64 + sc1 * 8];
    __syncthreads();

    auto step = [&](int kt, int cur, int nxt) {
        if (kt + 1 < 32) {
            *(bf16x8*)&Ks[nxt][wo0] = kreg0;
            *(bf16x8*)&Vs[nxt][wo0] = vreg0;
            *(bf16x8*)&Ks[nxt][wo1] = kreg1;
            *(bf16x8*)&Vs[nxt][wo1] = vreg1;
        }
        if (kt + 2 < 32) {
            int nk = (kt + 2) * 64;
            kreg0 = *(const bf16x8*)&Kn[(b * SEQ + nk + sr0) * 512 + h * 64 + sc0 * 8];
            vreg0 = *(const bf16x8*)&Vt[((long)(bh * 64 + sr0)) * SEQ + nk + sc0 * 8];
            kreg1 = *(const bf16x8*)&Kn[(b * SEQ + nk + sr1) * 512 + h * 64 + sc1 * 8];
            vreg1 = *(const bf16x8*)&Vt[((long)(bh * 64 + sr1)) * SEQ + nk + sc1 * 8];
        }

        // ---- S^T = K * Q^T on buf[cur]: accS[it] is 16k x 16q ----
        f32x4 accS[4];
#pragma unroll
        for (int it = 0; it < 4; ++it) accS[it] = (f32x4)0.f;

#pragma unroll
        for (int it = 0; it < 4; ++it) {
            bf16x8 kf[2];
#pragma unroll
            for (int ks = 0; ks < 2; ++ks)
                kf[ks] = *(const bf16x8*)&Ks[cur][(it * 16 + lo) * 64 +
                                                 (((ks * 4 + hi) ^ (lo & 7)) * 8)];
#pragma unroll
            for (int ks = 0; ks < 2; ++ks)
                accS[it] = __builtin_amdgcn_mfma_f32_16x16x32_bf16(
                    kf[ks], qfrag[ks], accS[it], 0, 0, 0);
        }

        // ---- p = 2^s; pack; b64 write ----
#pragma unroll
        for (int it = 0; it < 4; ++it) {
            float p0, p1, p2, p3;
            asm("v_exp_f32 %0, %1" : "=v"(p0) : "v"(accS[it][0]));
            asm("v_exp_f32 %0, %1" : "=v"(p1) : "v"(accS[it][1]));
            asm("v_exp_f32 %0, %1" : "=v"(p2) : "v"(accS[it][2]));
            asm("v_exp_f32 %0, %1" : "=v"(p3) : "v"(accS[it][3]));
            l_part += (p0 + p1) + (p2 + p3);
            unsigned w0, w1;
            asm("v_cvt_pk_bf16_f32 %0, %1, %2" : "=v"(w0) : "v"(p0), "v"(p1));
            asm("v_cvt_pk_bf16_f32 %0, %1, %2" : "=v"(w1) : "v"(p2), "v"(p3));
            int cch = it * 2 + (hi >> 1);
            int off = lo * 64 + ((cch ^ (lo & 7)) * 8) + (hi & 1) * 4;
            uint2 t; t.x = w0; t.y = w1;
            *(uint2*)&Ps[w][off] = t;
        }

        // ---- O += P[16q][64k] * V^T on buf[cur] ----
#pragma unroll
        for (int kk = 0; kk < 2; ++kk) {
            bf16x8 pf = *(const bf16x8*)&Ps[w][lo * 64 +
                                              (((kk * 4 + hi) ^ (lo & 7)) * 8)];
#pragma unroll
            for (int nt = 0; nt < 4; ++nt) {
                bf16x8 vf = *(const bf16x8*)&Vs[cur][(nt * 16 + lo) * 64 +
                                                    (((kk * 4 + hi) ^ (lo & 7)) * 8)];
                accO[nt] = __builtin_amdgcn_mfma_f32_16x16x32_bf16(
                    pf, vf, accO[nt], 0, 0, 0);
            }
        }
        __syncthreads();
    };

    for (int kt = 0; kt < 32; kt += 2) {
        step(kt, 0, 1);
        step(kt + 1, 1, 0);
    }

    l_part += __shfl_xor(l_part, 16);
    l_part += __shfl_xor(l_part, 32);

#pragma unroll
    for (int r = 0; r < 4; ++r) {
        float lq = __shfl(l_part, hi * 4 + r);
        int grow = b * SEQ + qb + hi * 4 + r;
        float g = bf2f(QKV[(long)grow * 1544 + 512 + h]);
        g = 1.f / (1.f + __expf(-g));
        float sc = g / lq;
#pragma unroll
        for (int nt = 0; nt < 4; ++nt)
            AO[(long)grow * 512 + h * 64 + nt * 16 + lo] = f2bf(accO[nt][r] * sc);
    }
}

// pos_out = ao @ whp + bias_po (bf16 in, fp32 fold weights)
__global__ __launch_bounds__(256) void posout_kernel(
    const ushort_t* __restrict__ ao, const float* __restrict__ whp,
    const float* __restrict__ bpo, float* __restrict__ po)
{
    const int lane = threadIdx.x & 63;
    const long row = (long)blockIdx.x * 4 + (threadIdx.x >> 6);
    float p0 = 0.f, p1 = 0.f, p2 = 0.f;
#pragma unroll
    for (int it = 0; it < 8; ++it) {
        int k = it * 64 + lane;
        float x = bf2f(ao[row * 512 + k]);
        p0 = fmaf(x, whp[k * 3 + 0], p0);
        p1 = fmaf(x, whp[k * 3 + 1], p1);
        p2 = fmaf(x, whp[k * 3 + 2], p2);
    }
#pragma unroll
    for (int o = 32; o >= 1; o >>= 1) {
        p0 += __shfl_xor(p0, o);
        p1 += __shfl_xor(p1, o);
        p2 += __shfl_xor(p2, o);
    }
    if (lane == 0) {
        po[row * 3 + 0] = p0 + bpo[0];
        po[row * 3 + 1] = p1 + bpo[1];
        po[row * 3 + 2] = p2 + bpo[2];
    }
}

// ---------------------------------------------------------------------------
extern "C" void kernel_launch(void* const* d_in, const int* in_sizes, int n_in,
                              void* d_out, int out_size, void* d_ws, size_t ws_size,
                              hipStream_t stream)
{
    const float* expr    = (const float*)d_in[0];
    const float* dtime   = (const float*)d_in[1];
    const float* posf    = (const float*)d_in[2];
    const float* pos_w1  = (const float*)d_in[3];
    const float* pos_b1  = (const float*)d_in[4];
    const float* pos_w2  = (const float*)d_in[5];
    const float* pos_b2  = (const float*)d_in[6];
    const float* expr_w1 = (const float*)d_in[7];
    const float* expr_b1 = (const float*)d_in[8];
    const float* expr_w2 = (const float*)d_in[9];
    const float* expr_b2 = (const float*)d_in[10];
    const float* yy_w    = (const float*)d_in[11];
    const float* yy_b    = (const float*)d_in[12];
    const float* cat_w   = (const float*)d_in[13];
    const float* cat_b   = (const float*)d_in[14];
    const float* q_w     = (const float*)d_in[15];
    const float* q_b     = (const float*)d_in[16];
    const float* k_w     = (const float*)d_in[17];
    const float* k_b     = (const float*)d_in[18];
    const float* v_w     = (const float*)d_in[19];
    const float* v_b     = (const float*)d_in[20];
    const float* o_w     = (const float*)d_in[21];
    const float* o_b     = (const float*)d_in[22];
    const float* qn_w    = (const float*)d_in[23];
    const float* kn_w    = (const float*)d_in[24];
    const float* hp_w    = (const float*)d_in[25];
    const float* hp_b    = (const float*)d_in[26];
    const float* he_w    = (const float*)d_in[27];
    const float* he_b    = (const float*)d_in[28];
    (void)in_sizes; (void)n_in; (void)out_size; (void)ws_size;

    ushort_t* wsb     = (ushort_t*)d_ws;
    ushort_t* expr_bf = wsb + U_EXPR;
    ushort_t* a192    = wsb + U_A192;
    ushort_t* h_bf    = wsb + U_H;
    ushort_t* qkv_bf  = wsb + U_QKV;
    ushort_t* kn_bf   = wsb + U_KN;
    ushort_t* vt_bf   = wsb + U_VT;
    ushort_t* ao_bf   = wsb + U_AO;
    ushort_t* w1t     = wsb + U_W1T;
    ushort_t* w2raw   = wsb + U_W2RAW;
    ushort_t* cat_wt  = wsb + U_CATWT;
    ushort_t* qkv_wt  = wsb + U_QKVWT;
    ushort_t* he_wt   = wsb + U_HEWT;
    ushort_t* wprime  = wsb + U_WPRIME;
    ushort_t* wohe    = wsb + U_WOHE;
    ushort_t* o_raw   = wsb + U_ORAW;
    float* f32r       = (float*)(wsb + U_F32);
    float* tdt        = f32r + F_TDT;
    float* qkv_bias   = f32r + F_QKVB;
    float* bias_h     = f32r + F_BIASH;
    float* bias_eo    = f32r + F_BIASEO;
    float* bias_po    = f32r + F_BIASPO;
    float* whp        = f32r + F_WHP;
    float* dout       = (float*)d_out;

    const dim3 blk(256);
    const dim3 blk512(512);

    // --- prep: all converts/transposes in ONE kernel ---
    WtTable tab;
    //            src              dst               K    N   tK tile0 dstS mode
    tab.s[0] = { expr_w1,          w1t,             512,  64,  8,   0, 512, 0 };  //   8
    tab.s[1] = { cat_w,            cat_wt,          768, 512, 12,   8, 768, 0 };  //  96
    tab.s[2] = { q_w,              qkv_wt,          512, 520,  8, 104, 512, 0 };  //  72
    tab.s[3] = { k_w,              qkv_wt + 520*512,512, 512,  8, 176, 512, 0 };  //  64
    tab.s[4] = { v_w,              qkv_wt +1032*512,512, 512,  8, 240, 512, 0 };  //  64
    tab.s[5] = { he_w,             he_wt,           512, 512,  8, 304, 512, 0 };  //  64
    tab.s[6] = { cat_w + 640*512,  wprime + 64,     128, 512,  2, 368, 192, 0 };  //  16
    tab.s[7] = { expr_w2,          w2raw,             0,   0,  0, 384,   0, 1 };  //   2
    tab.s[8] = { o_w,              o_raw,             0,   0,  0, 386,   0, 1 };  //  16
    tab.s[9] = { expr,             expr_bf,           0,   0,  0, 402,   0, 1 };  // 256 -> 658
    wt_transpose<<<dim3(665), blk, 0, stream>>>(tab, q_b, k_b, v_b, qkv_bias);

    tdt_kernel<<<dim3(1), dim3(512), 0, stream>>>(dtime, yy_w, yy_b, tdt,
                                                  dout + DOUT_TDT);
    biasfold_kernel<<<dim3(1025), blk, 0, stream>>>(
        cat_wt, he_wt, expr_b2, tdt, cat_b, o_b, he_b, o_w, hp_w, hp_b,
        bias_h, bias_eo, whp, bias_po);
    // W'[:, :64] = (expr_w2 @ cat_w0)^T rows
    hgemm<0, 1, 0, 0><<<dim3(1, 4), blk512, 0, stream>>>(cat_wt, 768, w2raw, 512,
                                                         nullptr, wprime, 192, 64, 512);
    // wohe[n][k] = sum_i he_w[i][n] * o_w[k][i]  (B-operand = NATIVE o_w)
    hgemm<0, 1, 0, 0><<<dim3(4, 4), blk512, 0, stream>>>(he_wt, 512, o_raw, 512,
                                                         nullptr, wohe, 512, 512, 512);

    // --- pipeline ---
    hgemm<1, 1, 1, 0><<<dim3(1, 64), blk512, 0, stream>>>(expr_bf, 512, w1t, 512,
                                                          expr_b1, a192, 192, 64, 512);
    posmlp_kernel<<<dim3(256), blk, 0, stream>>>(posf, pos_w1, pos_b1,
                                                 pos_w2, pos_b2, a192);
    hgemm<0, 1, 1, 512><<<dim3(4, 64), blk512, 0, stream>>>(a192, 192, wprime, 192,
                                                            bias_h, h_bf, 512, 512, 192);
    hgemm<0, 1, 1, 0><<<dim3(13, 64), blk512, 0, stream>>>(h_bf, 512, qkv_wt, 512,
                                                           qkv_bias, qkv_bf, 1544, 1544, 512);
    qkvpost_kernel<<<dim3(32, 32), blk, 0, stream>>>(qkv_bf, kn_w, kn_bf, vt_bf);
    flash_attn_mfma<<<dim3(32, 32), blk, 0, stream>>>(qkv_bf, kn_bf, vt_bf, qn_w, ao_bf);
    hgemm<0, 0, 1, 0><<<dim3(4, 64), blk512, 0, stream>>>(ao_bf, 512, wohe, 512,
                                                          bias_eo, dout + DOUT_EXPR,
                                                          512, 512, 512);
    posout_kernel<<<dim3(2048), blk, 0, stream>>>(ao_bf, whp, bias_po,
                                                  dout + DOUT_POS);
}

// Round 12
// 166.692 us; speedup vs baseline: 1.0542x; 1.0542x over previous
//
#include <hip/hip_runtime.h>
#include <math.h>

// Problem constants
#define SEQ   2048
#define NROWS 8192   // B*N

typedef unsigned short ushort_t;
typedef __attribute__((ext_vector_type(8))) short bf16x8;
typedef __attribute__((ext_vector_type(4))) float f32x4;

// Workspace offsets (ushort units)
#define U_EXPR   0ull            // 8192*512
#define U_A192   4194304ull      // 8192*192  ([te1|tp])
#define U_H      5767168ull      // 8192*512
#define U_QKV    9961472ull      // 8192*1544
#define U_KN     26804224ull     // 8192*512
#define U_VT     30998528ull     // 32*64*2048
#define U_AO     35192832ull     // 8192*512
#define U_W1T    39387136ull     // 64*512
#define U_W2RAW  39419904ull     // 64*512
#define U_CATWT  39452672ull     // 512*768
#define U_QKVWT  39845888ull     // 1544*512
#define U_HEWT   40898560ull     // 512*512
#define U_WPRIME 41160704ull     // 512*192
#define U_WOHE   41259008ull     // 512*512
#define U_F32    41521152ull     // fp32 region (8192 floats)
#define U_ORAW   41537536ull     // 512*512 bf16, o_w native layout

// fp32 region layout (float offsets)
#define F_TDT    0
#define F_QKVB   512
#define F_BIASH  2056    // [4][512]
#define F_BIASEO 4104    // [512]
#define F_BIASPO 4616    // [4]
#define F_WHP    4620    // [512][3]

// d_out offsets (floats): (expr_out, pos_out, tdt)
#define DOUT_EXPR 0ull
#define DOUT_POS  4194304ull
#define DOUT_TDT  4218880ull

#define LOG2E 1.44269504088896340736f

static __device__ __forceinline__ ushort_t f2bf(float f) {
    union { float f; unsigned int u; } v; v.f = f;
    unsigned int r = (v.u + 0x7fffu + ((v.u >> 16) & 1u)) >> 16;
    return (ushort_t)r;
}
static __device__ __forceinline__ float bf2f(ushort_t u) {
    union { unsigned int u; float f; } v; v.u = ((unsigned int)u) << 16;
    return v.f;
}

// async global->LDS, 16B per lane; LDS dest = wave-uniform base + lane*16
static __device__ __forceinline__ void gload16(const void* g, void* l) {
    __builtin_amdgcn_global_load_lds(
        (const __attribute__((address_space(1))) void*)g,
        (__attribute__((address_space(3))) void*)l,
        16, 0, 0);
}

// ---------------------------------------------------------------------------
// Weight prep: mode 0 = transpose 64x64 tile (src[K][N] -> dst[n*dstStride+k]),
// mode 1 = convert-copy 16384-elem tile. Blocks >= 658: qkv bias gather.
// ---------------------------------------------------------------------------
struct WtSeg { const float* src; ushort_t* dst; int K, N, tK, tile0, dstStride, mode; };
struct WtTable { WtSeg s[10]; };

__global__ __launch_bounds__(256) void wt_transpose(
    WtTable tab, const float* __restrict__ qb, const float* __restrict__ kb,
    const float* __restrict__ vb, float* __restrict__ bias_dst)
{
    const int bid = blockIdx.x;
    const int tid = threadIdx.x;
    if (bid >= 658) {
        int t = (bid - 658) * 256 + tid;
        if (t < 520) bias_dst[t] = qb[t];
        else if (t < 1032) bias_dst[t] = kb[t - 520];
        else if (t < 1544) bias_dst[t] = vb[t - 1032];
        return;
    }
    int si = 0;
#pragma unroll
    for (int i = 1; i < 10; ++i)
        if (bid >= tab.s[i].tile0) si = i;
    const WtSeg sg = tab.s[si];
    const int local = bid - sg.tile0;

    if (sg.mode == 1) {
        long base = (long)local * 16384;
#pragma unroll
        for (int i = 0; i < 8; ++i) {
            long p = base + i * 2048 + tid * 8;
            float4 a = *(const float4*)&sg.src[p];
            float4 b = *(const float4*)&sg.src[p + 4];
            bf16x8 o;
            o[0] = (short)f2bf(a.x); o[1] = (short)f2bf(a.y);
            o[2] = (short)f2bf(a.z); o[3] = (short)f2bf(a.w);
            o[4] = (short)f2bf(b.x); o[5] = (short)f2bf(b.y);
            o[6] = (short)f2bf(b.z); o[7] = (short)f2bf(b.w);
            *(bf16x8*)&sg.dst[p] = o;
        }
        return;
    }

    __shared__ float t[64][65];
    const int k0 = (local % sg.tK) * 64;
    const int n0 = (local / sg.tK) * 64;
#pragma unroll
    for (int i = 0; i < 16; ++i) {
        int e = tid + i * 256;
        int r = e >> 6, c = e & 63;
        float v = 0.f;
        if (k0 + r < sg.K && n0 + c < sg.N)
            v = sg.src[(long)(k0 + r) * sg.N + n0 + c];
        t[r][c] = v;
    }
    __syncthreads();
#pragma unroll
    for (int i = 0; i < 16; ++i) {
        int e = tid + i * 256;
        int rn = e >> 6, ck = e & 63;
        if (n0 + rn < sg.N && k0 + ck < sg.K)
            sg.dst[(long)(n0 + rn) * sg.dstStride + k0 + ck] = f2bf(t[ck][rn]);
    }
}

// ---------------------------------------------------------------------------
// Bias folding (wave-per-output) — unchanged.
// ---------------------------------------------------------------------------
__global__ __launch_bounds__(256) void biasfold_kernel(
    const ushort_t* __restrict__ catwt, const ushort_t* __restrict__ hewt,
    const float* __restrict__ expr_b2, const float* __restrict__ tdt,
    const float* __restrict__ cat_b, const float* __restrict__ o_b,
    const float* __restrict__ he_b, const float* __restrict__ o_w,
    const float* __restrict__ hp_w, const float* __restrict__ hp_b,
    float* __restrict__ bias_h, float* __restrict__ bias_eo,
    float* __restrict__ whp, float* __restrict__ bias_po)
{
    const int wid = blockIdx.x * 4 + (threadIdx.x >> 6);
    const int lane = threadIdx.x & 63;
    float s = 0.f;
    if (wid < 2048) {
        int b = wid >> 9, n = wid & 511;
        bf16x8 wv = *(const bf16x8*)&catwt[(long)n * 768 + lane * 8];
        float4 e0 = *(const float4*)&expr_b2[lane * 8];
        float4 e1 = *(const float4*)&expr_b2[lane * 8 + 4];
        s = bf2f((ushort_t)wv[0]) * e0.x + bf2f((ushort_t)wv[1]) * e0.y +
            bf2f((ushort_t)wv[2]) * e0.z + bf2f((ushort_t)wv[3]) * e0.w +
            bf2f((ushort_t)wv[4]) * e1.x + bf2f((ushort_t)wv[5]) * e1.y +
            bf2f((ushort_t)wv[6]) * e1.z + bf2f((ushort_t)wv[7]) * e1.w;
        float2 tt = *(const float2*)&tdt[b * 128 + lane * 2];
        s += bf2f(catwt[(long)n * 768 + 512 + lane * 2]) * tt.x;
        s += bf2f(catwt[(long)n * 768 + 513 + lane * 2]) * tt.y;
#pragma unroll
        for (int o = 32; o >= 1; o >>= 1) s += __shfl_xor(s, o);
        if (lane == 0) bias_h[b * 512 + n] = s + cat_b[n];
    } else if (wid < 2560) {
        int n = wid - 2048;
        bf16x8 wv = *(const bf16x8*)&hewt[(long)n * 512 + lane * 8];
        float4 e0 = *(const float4*)&o_b[lane * 8];
        float4 e1 = *(const float4*)&o_b[lane * 8 + 4];
        s = bf2f((ushort_t)wv[0]) * e0.x + bf2f((ushort_t)wv[1]) * e0.y +
            bf2f((ushort_t)wv[2]) * e0.z + bf2f((ushort_t)wv[3]) * e0.w +
            bf2f((ushort_t)wv[4]) * e1.x + bf2f((ushort_t)wv[5]) * e1.y +
            bf2f((ushort_t)wv[6]) * e1.z + bf2f((ushort_t)wv[7]) * e1.w;
#pragma unroll
        for (int o = 32; o >= 1; o >>= 1) s += __shfl_xor(s, o);
        if (lane == 0) bias_eo[n] = s + he_b[n];
    } else if (wid < 4096) {
        int t = wid - 2560;
        int c = t >> 9, k = t & 511;
#pragma unroll
        for (int i = 0; i < 8; ++i) {
            int j = i * 64 + lane;
            s = fmaf(o_w[(long)k * 512 + j], hp_w[j * 3 + c], s);
        }
#pragma unroll
        for (int o = 32; o >= 1; o >>= 1) s += __shfl_xor(s, o);
        if (lane == 0) whp[k * 3 + c] = s;
    } else if (wid < 4099) {
        int c = wid - 4096;
#pragma unroll
        for (int i = 0; i < 8; ++i) {
            int j = i * 64 + lane;
            s = fmaf(o_b[j], hp_w[j * 3 + c], s);
        }
#pragma unroll
        for (int o = 32; o >= 1; o >>= 1) s += __shfl_xor(s, o);
        if (lane == 0) bias_po[c] = s + hp_b[c];
    }
}

// ---------------------------------------------------------------------------
// bf16 MFMA GEMM, double-buffered LDS + ONE barrier per K-step (flash r9
// pattern): issue gloads(t+1) -> buf[nxt] before computing buf[cur]; barrier
// drains the async loads after they flew under the MFMA phase. LDS 64KB.
// ---------------------------------------------------------------------------
template <int RELU, int OUT_BF16, int HASBIAS, int BBSTRIDE>
__global__ __launch_bounds__(512) void hgemm(
    const ushort_t* __restrict__ A, int lda,
    const ushort_t* __restrict__ Wt, int ldw,
    const float* __restrict__ bias,
    void* __restrict__ Cv, int ldc,
    int N, int K)
{
    __shared__ __align__(16) ushort_t As[2][128 * 64];
    __shared__ __align__(16) ushort_t Bs[2][128 * 64];

    const int tid = threadIdx.x;
    const int lane = tid & 63, w = tid >> 6;
    const int lo = lane & 15, hi = lane >> 4;
    const int wm = w >> 2, wn = w & 3;
    const long m0 = (long)blockIdx.y * 128;
    const int n0 = blockIdx.x * 128;

    f32x4 acc[4][2];
#pragma unroll
    for (int mt = 0; mt < 4; ++mt)
#pragma unroll
        for (int nt = 0; nt < 2; ++nt) acc[mt][nt] = (f32x4)0.f;

    auto stage = [&](int kt, int buf) {
#pragma unroll
        for (int i = 0; i < 2; ++i) {
            int c = w * 128 + i * 64 + lane;
            int r = c >> 3, ch = c & 7;
            int sch = ch ^ (r & 7);
            gload16(&A[(m0 + r) * (long)lda + kt + sch * 8],
                    &As[buf][(w * 128 + i * 64) * 8]);
            gload16(&Wt[(long)(n0 + r) * ldw + kt + sch * 8],
                    &Bs[buf][(w * 128 + i * 64) * 8]);
        }
    };

    stage(0, 0);
    __syncthreads();

    int cur = 0;
    for (int kt = 0; kt < K; kt += 64) {
        if (kt + 64 < K) stage(kt + 64, cur ^ 1);

#pragma unroll
        for (int ks = 0; ks < 2; ++ks) {
            bf16x8 af[4], bfr[2];
#pragma unroll
            for (int mt = 0; mt < 4; ++mt) {
                int m = wm * 64 + mt * 16 + lo;
                af[mt] = *(const bf16x8*)&As[cur][m * 64 + (((ks * 4 + hi) ^ (lo & 7)) * 8)];
            }
#pragma unroll
            for (int nt = 0; nt < 2; ++nt) {
                int n = wn * 32 + nt * 16 + lo;
                bfr[nt] = *(const bf16x8*)&Bs[cur][n * 64 + (((ks * 4 + hi) ^ (lo & 7)) * 8)];
            }
#pragma unroll
            for (int mt = 0; mt < 4; ++mt)
#pragma unroll
                for (int nt = 0; nt < 2; ++nt)
                    acc[mt][nt] = __builtin_amdgcn_mfma_f32_16x16x32_bf16(
                        af[mt], bfr[nt], acc[mt][nt], 0, 0, 0);
        }
        __syncthreads();
        cur ^= 1;
    }

#pragma unroll
    for (int mt = 0; mt < 4; ++mt)
#pragma unroll
        for (int nt = 0; nt < 2; ++nt) {
            int col = n0 + wn * 32 + nt * 16 + lo;
            if (col < N) {
                float bv = 0.f;
                if (HASBIAS)
                    bv = BBSTRIDE ? bias[(int)(m0 >> 11) * BBSTRIDE + col] : bias[col];
#pragma unroll
                for (int r = 0; r < 4; ++r) {
                    long row = m0 + wm * 64 + mt * 16 + hi * 4 + r;
                    float v = acc[mt][nt][r] + bv;
                    if (RELU) v = fmaxf(v, 0.f);
                    if (OUT_BF16) ((ushort_t*)Cv)[row * (long)ldc + col] = f2bf(v);
                    else          ((float*)Cv)[row * (long)ldc + col] = v;
                }
            }
        }
}

// ---------------------------------------------------------------------------
// Position MLP -> a192[:, 64:192] (bf16) — round-10 parallel version.
// ---------------------------------------------------------------------------
__global__ __launch_bounds__(256) void posmlp_kernel(
    const float* __restrict__ pos,
    const float* __restrict__ w1, const float* __restrict__ b1,
    const float* __restrict__ w2, const float* __restrict__ b2,
    ushort_t* __restrict__ a192)
{
    __shared__ __align__(16) float w1s[256];
    __shared__ __align__(16) float b1s[64];
    __shared__ __align__(16) float w2t[128 * 72];
    __shared__ __align__(16) float b2s[128];

    const int tid = threadIdx.x;
    w1s[tid] = w1[tid];
    if (tid < 64) b1s[tid] = b1[tid];
    if (tid < 128) b2s[tid] = b2[tid];
    for (int i = tid; i < 8192; i += 256) {
        int k = i >> 7, o = i & 127;
        w2t[o * 72 + k] = w2[i];
    }
    __syncthreads();

    const long r = (long)blockIdx.x * 32 + (tid >> 3);
    const int chunk = tid & 7;
    float px = pos[r * 3 + 0], py = pos[r * 3 + 1], pz = pos[r * 3 + 2];
    float nrm = sqrtf(px * px + py * py + pz * pz);
    float inv = 1.f / (nrm + 1e-7f);
    float pf0 = px * inv, pf1 = py * inv, pf2 = pz * inv, pf3 = nrm;

    float h1[64];
#pragma unroll
    for (int o = 0; o < 64; ++o) {
        float a = b1s[o];
        a = fmaf(pf0, w1s[o], a);
        a = fmaf(pf1, w1s[64 + o], a);
        a = fmaf(pf2, w1s[128 + o], a);
        a = fmaf(pf3, w1s[192 + o], a);
        h1[o] = fmaxf(a, 0.f);
    }
    ushort_t* dst = &a192[r * 192 + 64];
#pragma unroll
    for (int j = 0; j < 16; ++j) {
        int o = chunk + 8 * j;
        float s = b2s[o];
#pragma unroll
        for (int i4 = 0; i4 < 16; ++i4) {
            float4 wv = *(const float4*)&w2t[o * 72 + i4 * 4];
            s = fmaf(h1[i4 * 4 + 0], wv.x, s);
            s = fmaf(h1[i4 * 4 + 1], wv.y, s);
            s = fmaf(h1[i4 * 4 + 2], wv.z, s);
            s = fmaf(h1[i4 * 4 + 3], wv.w, s);
        }
        dst[o] = f2bf(s);
    }
}

// tdt = diffusion_time @ yy_w + yy_b (fp32, exact)
__global__ __launch_bounds__(512) void tdt_kernel(
    const float* __restrict__ dt, const float* __restrict__ yyw,
    const float* __restrict__ yyb, float* __restrict__ tdt_ws,
    float* __restrict__ out_tail)
{
    const int t = threadIdx.x;
    const int b = t >> 7, o = t & 127;
    float s = yyb[o];
    for (int k = 0; k < 128; ++k) s = fmaf(dt[b * 128 + k], yyw[k * 128 + o], s);
    tdt_ws[t] = s;
    out_tail[t] = s;
}

// ---------------------------------------------------------------------------
// qkv postprocess: K rmsnorm + V transpose — unchanged.
// ---------------------------------------------------------------------------
__global__ __launch_bounds__(256) void qkvpost_kernel(
    const ushort_t* __restrict__ qkv, const float* __restrict__ knw,
    ushort_t* __restrict__ kn, ushort_t* __restrict__ Vt)
{
    __shared__ ushort_t t[64][72];
    __shared__ float knw_s[64];
    const int bh = blockIdx.x, b = bh >> 3, h = bh & 7;
    const int n0 = blockIdx.y * 64;
    const int tid = threadIdx.x;
    if (tid < 64) knw_s[tid] = knw[tid];
#pragma unroll
    for (int i = 0; i < 2; ++i) {
        int c = tid + i * 256;
        int r = c >> 3, ch = c & 7;
        *(bf16x8*)&t[r][ch * 8] =
            *(const bf16x8*)&qkv[(long)(b * SEQ + n0 + r) * 1544 + 1032 + h * 64 + ch * 8];
    }
    __syncthreads();
#pragma unroll
    for (int i = 0; i < 2; ++i) {
        int c = tid + i * 256;
        int r = c >> 3, ch = c & 7;
        bf16x8 kv = *(const bf16x8*)&qkv[(long)(b * SEQ + n0 + r) * 1544 + 520 + h * 64 + ch * 8];
        float x[8], ss = 0.f;
#pragma unroll
        for (int j = 0; j < 8; ++j) { x[j] = bf2f((ushort_t)kv[j]); ss = fmaf(x[j], x[j], ss); }
        ss += __shfl_xor(ss, 1);
        ss += __shfl_xor(ss, 2);
        ss += __shfl_xor(ss, 4);
        float invr = rsqrtf(ss * (1.f / 64.f) + 1e-6f);
        bf16x8 o;
#pragma unroll
        for (int j = 0; j < 8; ++j) o[j] = (short)f2bf(x[j] * knw_s[ch * 8 + j] * invr);
        *(bf16x8*)&kn[(long)(b * SEQ + n0 + r) * 512 + h * 64 + ch * 8] = o;
    }
    const int d = tid >> 2;
#pragma unroll
    for (int i = 0; i < 2; ++i) {
        int cc = (tid & 3) * 2 + i;
        bf16x8 pk;
#pragma unroll
        for (int j = 0; j < 8; ++j) pk[j] = (short)t[cc * 8 + j][d];
        *(bf16x8*)&Vt[((long)(bh * 64 + d)) * SEQ + n0 + cc * 8] = pk;
    }
}

// ---------------------------------------------------------------------------
// Flash attention — REVERTED to round-10 measured-good config (53.2 us):
// 32 q-rows/wave, grid (32,16), double-buffered K/V, 1 barrier/K-tile,
// inline Q rmsnorm, exp2-domain softmax via raw v_exp_f32, packed P writes.
// (Round-11's 16 q/wave regressed: halves MFMA per LDS read.)
// ---------------------------------------------------------------------------
__global__ __launch_bounds__(256) void flash_attn_mfma(
    const ushort_t* __restrict__ QKV, const ushort_t* __restrict__ Kn,
    const ushort_t* __restrict__ Vt, const float* __restrict__ qnw,
    ushort_t* __restrict__ AO)
{
    __shared__ __align__(16) ushort_t Ks[2][64 * 64];
    __shared__ __align__(16) ushort_t Vs[2][64 * 64];
    __shared__ __align__(16) ushort_t Ps[4][32 * 64];

    const int tid = threadIdx.x;
    const int lane = tid & 63;
    const int w = tid >> 6;
    const int lo = lane & 15, hi = lane >> 4;
    const int bh = blockIdx.x, b = bh >> 3, h = bh & 7;
    const int qb = blockIdx.y * 128 + w * 32;

    bf16x8 qfrag[2][2];
    {
        float qw[2][8];
#pragma unroll
        for (int ks = 0; ks < 2; ++ks)
#pragma unroll
            for (int j = 0; j < 8; ++j)
                qw[ks][j] = qnw[ks * 32 + hi * 8 + j];
#pragma unroll
        for (int jt = 0; jt < 2; ++jt) {
            float qx[2][8], ss = 0.f;
#pragma unroll
            for (int ks = 0; ks < 2; ++ks) {
                bf16x8 q = *(const bf16x8*)&QKV[(long)(b * SEQ + qb + jt * 16 + lo) * 1544 +
                                                h * 64 + ks * 32 + hi * 8];
#pragma unroll
                for (int j = 0; j < 8; ++j) {
                    qx[ks][j] = bf2f((ushort_t)q[j]);
                    ss = fmaf(qx[ks][j], qx[ks][j], ss);
                }
            }
            ss += __shfl_xor(ss, 16);
            ss += __shfl_xor(ss, 32);
            float invr = rsqrtf(ss * (1.f / 64.f) + 1e-6f) * (0.125f * LOG2E);
#pragma unroll
            for (int ks = 0; ks < 2; ++ks) {
                bf16x8 f;
#pragma unroll
                for (int j = 0; j < 8; ++j)
                    f[j] = (short)f2bf(qx[ks][j] * qw[ks][j] * invr);
                qfrag[jt][ks] = f;
            }
        }
    }

    f32x4 accO[2][4];
#pragma unroll
    for (int mt = 0; mt < 2; ++mt)
#pragma unroll
        for (int nt = 0; nt < 4; ++nt) accO[mt][nt] = (f32x4)0.f;
    float l_part[2] = {0.f, 0.f};

    const int sr0 = tid >> 3, sc0 = tid & 7;
    const int sr1 = (tid + 256) >> 3, sc1 = tid & 7;
    const int wo0 = sr0 * 64 + ((sc0 ^ (sr0 & 7)) * 8);
    const int wo1 = sr1 * 64 + ((sc1 ^ (sr1 & 7)) * 8);

    bf16x8 kreg0, kreg1, vreg0, vreg1;
    kreg0 = *(const bf16x8*)&Kn[(b * SEQ + sr0) * 512 + h * 64 + sc0 * 8];
    vreg0 = *(const bf16x8*)&Vt[((long)(bh * 64 + sr0)) * SEQ + sc0 * 8];
    kreg1 = *(const bf16x8*)&Kn[(b * SEQ + sr1) * 512 + h * 64 + sc1 * 8];
    vreg1 = *(const bf16x8*)&Vt[((long)(bh * 64 + sr1)) * SEQ + sc1 * 8];
    *(bf16x8*)&Ks[0][wo0] = kreg0;
    *(bf16x8*)&Vs[0][wo0] = vreg0;
    *(bf16x8*)&Ks[0][wo1] = kreg1;
    *(bf16x8*)&Vs[0][wo1] = vreg1;
    kreg0 = *(const bf16x8*)&Kn[(b * SEQ + 64 + sr0) * 512 + h * 64 + sc0 * 8];
    vreg0 = *(const bf16x8*)&Vt[((long)(bh * 64 + sr0)) * SEQ + 64 + sc0 * 8];
    kreg1 = *(const bf16x8*)&Kn[(b * SEQ + 64 + sr1) * 512 + h * 64 + sc1 * 8];
    vreg1 = *(const bf16x8*)&Vt[((long)(bh * 64 + sr1)) * SEQ + 64 + sc1 * 8];
    __syncthreads();

    auto step = [&](int kt, int cur, int nxt) {
        if (kt + 1 < 32) {
            *(bf16x8*)&Ks[nxt][wo0] = kreg0;
            *(bf16x8*)&Vs[nxt][wo0] = vreg0;
            *(bf16x8*)&Ks[nxt][wo1] = kreg1;
            *(bf16x8*)&Vs[nxt][wo1] = vreg1;
        }
        if (kt + 2 < 32) {
            int nk = (kt + 2) * 64;
            kreg0 = *(const bf16x8*)&Kn[(b * SEQ + nk + sr0) * 512 + h * 64 + sc0 * 8];
            vreg0 = *(const bf16x8*)&Vt[((long)(bh * 64 + sr0)) * SEQ + nk + sc0 * 8];
            kreg1 = *(const bf16x8*)&Kn[(b * SEQ + nk + sr1) * 512 + h * 64 + sc1 * 8];
            vreg1 = *(const bf16x8*)&Vt[((long)(bh * 64 + sr1)) * SEQ + nk + sc1 * 8];
        }

        f32x4 accS[4][2];
#pragma unroll
        for (int it = 0; it < 4; ++it)
#pragma unroll
            for (int jt = 0; jt < 2; ++jt) accS[it][jt] = (f32x4)0.f;

#pragma unroll
        for (int it = 0; it < 4; ++it) {
            bf16x8 kf[2];
#pragma unroll
            for (int ks = 0; ks < 2; ++ks)
                kf[ks] = *(const bf16x8*)&Ks[cur][(it * 16 + lo) * 64 +
                                                 (((ks * 4 + hi) ^ (lo & 7)) * 8)];
#pragma unroll
            for (int jt = 0; jt < 2; ++jt)
#pragma unroll
                for (int ks = 0; ks < 2; ++ks)
                    accS[it][jt] = __builtin_amdgcn_mfma_f32_16x16x32_bf16(
                        kf[ks], qfrag[jt][ks], accS[it][jt], 0, 0, 0);
        }

#pragma unroll
        for (int it = 0; it < 4; ++it)
#pragma unroll
            for (int jt = 0; jt < 2; ++jt) {
                float p0, p1, p2, p3;
                asm("v_exp_f32 %0, %1" : "=v"(p0) : "v"(accS[it][jt][0]));
                asm("v_exp_f32 %0, %1" : "=v"(p1) : "v"(accS[it][jt][1]));
                asm("v_exp_f32 %0, %1" : "=v"(p2) : "v"(accS[it][jt][2]));
                asm("v_exp_f32 %0, %1" : "=v"(p3) : "v"(accS[it][jt][3]));
                l_part[jt] += (p0 + p1) + (p2 + p3);
                unsigned w0, w1;
                asm("v_cvt_pk_bf16_f32 %0, %1, %2" : "=v"(w0) : "v"(p0), "v"(p1));
                asm("v_cvt_pk_bf16_f32 %0, %1, %2" : "=v"(w1) : "v"(p2), "v"(p3));
                int q = jt * 16 + lo;
                int cch = it * 2 + (hi >> 1);
                int off = q * 64 + ((cch ^ (q & 7)) * 8) + (hi & 1) * 4;
                uint2 t; t.x = w0; t.y = w1;
                *(uint2*)&Ps[w][off] = t;
            }

#pragma unroll
        for (int kk = 0; kk < 2; ++kk) {
            bf16x8 pf[2];
#pragma unroll
            for (int mt = 0; mt < 2; ++mt)
                pf[mt] = *(const bf16x8*)&Ps[w][(mt * 16 + lo) * 64 +
                                               (((kk * 4 + hi) ^ (lo & 7)) * 8)];
#pragma unroll
            for (int nt = 0; nt < 4; ++nt) {
                bf16x8 vf = *(const bf16x8*)&Vs[cur][(nt * 16 + lo) * 64 +
                                                    (((kk * 4 + hi) ^ (lo & 7)) * 8)];
#pragma unroll
                for (int mt = 0; mt < 2; ++mt)
                    accO[mt][nt] = __builtin_amdgcn_mfma_f32_16x16x32_bf16(
                        pf[mt], vf, accO[mt][nt], 0, 0, 0);
            }
        }
        __syncthreads();
    };

    for (int kt = 0; kt < 32; kt += 2) {
        step(kt, 0, 1);
        step(kt + 1, 1, 0);
    }

#pragma unroll
    for (int jt = 0; jt < 2; ++jt) {
        l_part[jt] += __shfl_xor(l_part[jt], 16);
        l_part[jt] += __shfl_xor(l_part[jt], 32);
    }

#pragma unroll
    for (int mt = 0; mt < 2; ++mt)
#pragma unroll
        for (int r = 0; r < 4; ++r) {
            float lq = __shfl(l_part[mt], hi * 4 + r);
            int grow = b * SEQ + qb + mt * 16 + hi * 4 + r;
            float g = bf2f(QKV[(long)grow * 1544 + 512 + h]);
            g = 1.f / (1.f + __expf(-g));
            float sc = g / lq;
#pragma unroll
            for (int nt = 0; nt < 4; ++nt)
                AO[(long)grow * 512 + h * 64 + nt * 16 + lo] = f2bf(accO[mt][nt][r] * sc);
        }
}

// pos_out = ao @ whp + bias_po (bf16 in, fp32 fold weights)
__global__ __launch_bounds__(256) void posout_kernel(
    const ushort_t* __restrict__ ao, const float* __restrict__ whp,
    const float* __restrict__ bpo, float* __restrict__ po)
{
    const int lane = threadIdx.x & 63;
    const long row = (long)blockIdx.x * 4 + (threadIdx.x >> 6);
    float p0 = 0.f, p1 = 0.f, p2 = 0.f;
#pragma unroll
    for (int it = 0; it < 8; ++it) {
        int k = it * 64 + lane;
        float x = bf2f(ao[row * 512 + k]);
        p0 = fmaf(x, whp[k * 3 + 0], p0);
        p1 = fmaf(x, whp[k * 3 + 1], p1);
        p2 = fmaf(x, whp[k * 3 + 2], p2);
    }
#pragma unroll
    for (int o = 32; o >= 1; o >>= 1) {
        p0 += __shfl_xor(p0, o);
        p1 += __shfl_xor(p1, o);
        p2 += __shfl_xor(p2, o);
    }
    if (lane == 0) {
        po[row * 3 + 0] = p0 + bpo[0];
        po[row * 3 + 1] = p1 + bpo[1];
        po[row * 3 + 2] = p2 + bpo[2];
    }
}

// ---------------------------------------------------------------------------
extern "C" void kernel_launch(void* const* d_in, const int* in_sizes, int n_in,
                              void* d_out, int out_size, void* d_ws, size_t ws_size,
                              hipStream_t stream)
{
    const float* expr    = (const float*)d_in[0];
    const float* dtime   = (const float*)d_in[1];
    const float* posf    = (const float*)d_in[2];
    const float* pos_w1  = (const float*)d_in[3];
    const float* pos_b1  = (const float*)d_in[4];
    const float* pos_w2  = (const float*)d_in[5];
    const float* pos_b2  = (const float*)d_in[6];
    const float* expr_w1 = (const float*)d_in[7];
    const float* expr_b1 = (const float*)d_in[8];
    const float* expr_w2 = (const float*)d_in[9];
    const float* expr_b2 = (const float*)d_in[10];
    const float* yy_w    = (const float*)d_in[11];
    const float* yy_b    = (const float*)d_in[12];
    const float* cat_w   = (const float*)d_in[13];
    const float* cat_b   = (const float*)d_in[14];
    const float* q_w     = (const float*)d_in[15];
    const float* q_b     = (const float*)d_in[16];
    const float* k_w     = (const float*)d_in[17];
    const float* k_b     = (const float*)d_in[18];
    const float* v_w     = (const float*)d_in[19];
    const float* v_b     = (const float*)d_in[20];
    const float* o_w     = (const float*)d_in[21];
    const float* o_b     = (const float*)d_in[22];
    const float* qn_w    = (const float*)d_in[23];
    const float* kn_w    = (const float*)d_in[24];
    const float* hp_w    = (const float*)d_in[25];
    const float* hp_b    = (const float*)d_in[26];
    const float* he_w    = (const float*)d_in[27];
    const float* he_b    = (const float*)d_in[28];
    (void)in_sizes; (void)n_in; (void)out_size; (void)ws_size;

    ushort_t* wsb     = (ushort_t*)d_ws;
    ushort_t* expr_bf = wsb + U_EXPR;
    ushort_t* a192    = wsb + U_A192;
    ushort_t* h_bf    = wsb + U_H;
    ushort_t* qkv_bf  = wsb + U_QKV;
    ushort_t* kn_bf   = wsb + U_KN;
    ushort_t* vt_bf   = wsb + U_VT;
    ushort_t* ao_bf   = wsb + U_AO;
    ushort_t* w1t     = wsb + U_W1T;
    ushort_t* w2raw   = wsb + U_W2RAW;
    ushort_t* cat_wt  = wsb + U_CATWT;
    ushort_t* qkv_wt  = wsb + U_QKVWT;
    ushort_t* he_wt   = wsb + U_HEWT;
    ushort_t* wprime  = wsb + U_WPRIME;
    ushort_t* wohe    = wsb + U_WOHE;
    ushort_t* o_raw   = wsb + U_ORAW;
    float* f32r       = (float*)(wsb + U_F32);
    float* tdt        = f32r + F_TDT;
    float* qkv_bias   = f32r + F_QKVB;
    float* bias_h     = f32r + F_BIASH;
    float* bias_eo    = f32r + F_BIASEO;
    float* bias_po    = f32r + F_BIASPO;
    float* whp        = f32r + F_WHP;
    float* dout       = (float*)d_out;

    const dim3 blk(256);
    const dim3 blk512(512);

    // --- prep: all converts/transposes in ONE kernel ---
    WtTable tab;
    //            src              dst               K    N   tK tile0 dstS mode
    tab.s[0] = { expr_w1,          w1t,             512,  64,  8,   0, 512, 0 };  //   8
    tab.s[1] = { cat_w,            cat_wt,          768, 512, 12,   8, 768, 0 };  //  96
    tab.s[2] = { q_w,              qkv_wt,          512, 520,  8, 104, 512, 0 };  //  72
    tab.s[3] = { k_w,              qkv_wt + 520*512,512, 512,  8, 176, 512, 0 };  //  64
    tab.s[4] = { v_w,              qkv_wt +1032*512,512, 512,  8, 240, 512, 0 };  //  64
    tab.s[5] = { he_w,             he_wt,           512, 512,  8, 304, 512, 0 };  //  64
    tab.s[6] = { cat_w + 640*512,  wprime + 64,     128, 512,  2, 368, 192, 0 };  //  16
    tab.s[7] = { expr_w2,          w2raw,             0,   0,  0, 384,   0, 1 };  //   2
    tab.s[8] = { o_w,              o_raw,             0,   0,  0, 386,   0, 1 };  //  16
    tab.s[9] = { expr,             expr_bf,           0,   0,  0, 402,   0, 1 };  // 256 -> 658
    wt_transpose<<<dim3(665), blk, 0, stream>>>(tab, q_b, k_b, v_b, qkv_bias);

    tdt_kernel<<<dim3(1), dim3(512), 0, stream>>>(dtime, yy_w, yy_b, tdt,
                                                  dout + DOUT_TDT);
    biasfold_kernel<<<dim3(1025), blk, 0, stream>>>(
        cat_wt, he_wt, expr_b2, tdt, cat_b, o_b, he_b, o_w, hp_w, hp_b,
        bias_h, bias_eo, whp, bias_po);
    // W'[:, :64] = (expr_w2 @ cat_w0)^T rows
    hgemm<0, 1, 0, 0><<<dim3(1, 4), blk512, 0, stream>>>(cat_wt, 768, w2raw, 512,
                                                         nullptr, wprime, 192, 64, 512);
    // wohe[n][k] = sum_i he_w[i][n] * o_w[k][i]  (B-operand = NATIVE o_w)
    hgemm<0, 1, 0, 0><<<dim3(4, 4), blk512, 0, stream>>>(he_wt, 512, o_raw, 512,
                                                         nullptr, wohe, 512, 512, 512);

    // --- pipeline ---
    hgemm<1, 1, 1, 0><<<dim3(1, 64), blk512, 0, stream>>>(expr_bf, 512, w1t, 512,
                                                          expr_b1, a192, 192, 64, 512);
    posmlp_kernel<<<dim3(256), blk, 0, stream>>>(posf, pos_w1, pos_b1,
                                                 pos_w2, pos_b2, a192);
    hgemm<0, 1, 1, 512><<<dim3(4, 64), blk512, 0, stream>>>(a192, 192, wprime, 192,
                                                            bias_h, h_bf, 512, 512, 192);
    hgemm<0, 1, 1, 0><<<dim3(13, 64), blk512, 0, stream>>>(h_bf, 512, qkv_wt, 512,
                                                           qkv_bias, qkv_bf, 1544, 1544, 512);
    qkvpost_kernel<<<dim3(32, 32), blk, 0, stream>>>(qkv_bf, kn_w, kn_bf, vt_bf);
    flash_attn_mfma<<<dim3(32, 16), blk, 0, stream>>>(qkv_bf, kn_bf, vt_bf, qn_w, ao_bf);
    hgemm<0, 0, 1, 0><<<dim3(4, 64), blk512, 0, stream>>>(ao_bf, 512, wohe, 512,
                                                          bias_eo, dout + DOUT_EXPR,
                                                          512, 512, 512);
    posout_kernel<<<dim3(2048), blk, 0, stream>>>(ao_bf, whp, bias_po,
                                                  dout + DOUT_POS);
}

// Round 13
// 135.184 us; speedup vs baseline: 1.2999x; 1.2331x over previous
//
#include <hip/hip_runtime.h>
#include <math.h>

// Problem constants
#define SEQ   2048
#define NROWS 8192   // B*N

typedef unsigned short ushort_t;
typedef __attribute__((ext_vector_type(8))) short bf16x8;
typedef __attribute__((ext_vector_type(4))) float f32x4;

// Workspace offsets (ushort units)
#define U_EXPR   0ull            // 8192*512
#define U_A192   4194304ull      // 8192*192  ([te1|tp])
#define U_H      5767168ull      // 8192*512
#define U_QKV    9961472ull      // 8192*1544
#define U_KN     26804224ull     // 8192*512
#define U_VT     30998528ull     // 32*64*2048
#define U_AO     35192832ull     // 8192*512
#define U_W1T    39387136ull     // 64*512
#define U_W2RAW  39419904ull     // 64*512
#define U_CATWT  39452672ull     // 512*768
#define U_QKVWT  39845888ull     // 1544*512
#define U_HEWT   40898560ull     // 512*512
#define U_WPRIME 41160704ull     // 512*192
#define U_WOHE   41259008ull     // 512*512
#define U_F32    41521152ull     // fp32 region (8192 floats)
#define U_ORAW   41537536ull     // 512*512 bf16, o_w native layout

// fp32 region layout (float offsets)
#define F_TDT    0
#define F_QKVB   512
#define F_BIASH  2056    // [4][512]
#define F_BIASEO 4104    // [512]
#define F_BIASPO 4616    // [4]
#define F_WHP    4620    // [512][3]

// d_out offsets (floats): (expr_out, pos_out, tdt)
#define DOUT_EXPR 0ull
#define DOUT_POS  4194304ull
#define DOUT_TDT  4218880ull

#define LOG2E 1.44269504088896340736f

static __device__ __forceinline__ ushort_t f2bf(float f) {
    union { float f; unsigned int u; } v; v.f = f;
    unsigned int r = (v.u + 0x7fffu + ((v.u >> 16) & 1u)) >> 16;
    return (ushort_t)r;
}
static __device__ __forceinline__ float bf2f(ushort_t u) {
    union { unsigned int u; float f; } v; v.u = ((unsigned int)u) << 16;
    return v.f;
}

// async global->LDS, 16B per lane; LDS dest = wave-uniform base + lane*16
static __device__ __forceinline__ void gload16(const void* g, void* l) {
    __builtin_amdgcn_global_load_lds(
        (const __attribute__((address_space(1))) void*)g,
        (__attribute__((address_space(3))) void*)l,
        16, 0, 0);
}

// ---------------------------------------------------------------------------
// hgemm body (device fn): C[128M x 128N tile] = A @ Wt^T + bias.
// Double-buffered LDS (caller provides 64KB: As 2x8192, Bs 2x8192 ushorts),
// global_load_lds staging (swizzled source), one barrier per K-step.
// 512 threads. BBSTRIDE!=0: per-batch bias (2048 rows/batch).
// ---------------------------------------------------------------------------
template <int RELU, int OUT_BF16, int HASBIAS, int BBSTRIDE>
static __device__ void hgemm_body(
    const ushort_t* __restrict__ A, int lda,
    const ushort_t* __restrict__ Wt, int ldw,
    const float* __restrict__ bias,
    void* __restrict__ Cv, int ldc,
    int N, int K, int bx, int by,
    ushort_t* AsB, ushort_t* BsB)
{
    const int tid = threadIdx.x;
    const int lane = tid & 63, w = tid >> 6;
    const int lo = lane & 15, hi = lane >> 4;
    const int wm = w >> 2, wn = w & 3;
    const long m0 = (long)by * 128;
    const int n0 = bx * 128;

    f32x4 acc[4][2];
#pragma unroll
    for (int mt = 0; mt < 4; ++mt)
#pragma unroll
        for (int nt = 0; nt < 2; ++nt) acc[mt][nt] = (f32x4)0.f;

    auto stage = [&](int kt, int buf) {
#pragma unroll
        for (int i = 0; i < 2; ++i) {
            int c = w * 128 + i * 64 + lane;
            int r = c >> 3, ch = c & 7;
            int sch = ch ^ (r & 7);
            gload16(&A[(m0 + r) * (long)lda + kt + sch * 8],
                    &AsB[buf * 8192 + (w * 128 + i * 64) * 8]);
            gload16(&Wt[(long)(n0 + r) * ldw + kt + sch * 8],
                    &BsB[buf * 8192 + (w * 128 + i * 64) * 8]);
        }
    };

    stage(0, 0);
    __syncthreads();

    int cur = 0;
    for (int kt = 0; kt < K; kt += 64) {
        if (kt + 64 < K) stage(kt + 64, cur ^ 1);

#pragma unroll
        for (int ks = 0; ks < 2; ++ks) {
            bf16x8 af[4], bfr[2];
#pragma unroll
            for (int mt = 0; mt < 4; ++mt) {
                int m = wm * 64 + mt * 16 + lo;
                af[mt] = *(const bf16x8*)&AsB[cur * 8192 + m * 64 +
                                              (((ks * 4 + hi) ^ (lo & 7)) * 8)];
            }
#pragma unroll
            for (int nt = 0; nt < 2; ++nt) {
                int n = wn * 32 + nt * 16 + lo;
                bfr[nt] = *(const bf16x8*)&BsB[cur * 8192 + n * 64 +
                                               (((ks * 4 + hi) ^ (lo & 7)) * 8)];
            }
#pragma unroll
            for (int mt = 0; mt < 4; ++mt)
#pragma unroll
                for (int nt = 0; nt < 2; ++nt)
                    acc[mt][nt] = __builtin_amdgcn_mfma_f32_16x16x32_bf16(
                        af[mt], bfr[nt], acc[mt][nt], 0, 0, 0);
        }
        __syncthreads();
        cur ^= 1;
    }

#pragma unroll
    for (int mt = 0; mt < 4; ++mt)
#pragma unroll
        for (int nt = 0; nt < 2; ++nt) {
            int col = n0 + wn * 32 + nt * 16 + lo;
            if (col < N) {
                float bv = 0.f;
                if (HASBIAS)
                    bv = BBSTRIDE ? bias[(int)(m0 >> 11) * BBSTRIDE + col] : bias[col];
#pragma unroll
                for (int r = 0; r < 4; ++r) {
                    long row = m0 + wm * 64 + mt * 16 + hi * 4 + r;
                    float v = acc[mt][nt][r] + bv;
                    if (RELU) v = fmaxf(v, 0.f);
                    if (OUT_BF16) ((ushort_t*)Cv)[row * (long)ldc + col] = f2bf(v);
                    else          ((float*)Cv)[row * (long)ldc + col] = v;
                }
            }
        }
}

// Standalone hgemm kernel (h-GEMM, qkv-GEMM)
template <int RELU, int OUT_BF16, int HASBIAS, int BBSTRIDE>
__global__ __launch_bounds__(512) void hgemm(
    const ushort_t* __restrict__ A, int lda,
    const ushort_t* __restrict__ Wt, int ldw,
    const float* __restrict__ bias,
    void* __restrict__ Cv, int ldc, int N, int K)
{
    __shared__ __align__(16) ushort_t ls[32768];
    hgemm_body<RELU, OUT_BF16, HASBIAS, BBSTRIDE>(
        A, lda, Wt, ldw, bias, Cv, ldc, N, K,
        blockIdx.x, blockIdx.y, ls, ls + 16384);
}

// ---------------------------------------------------------------------------
// Prep1: weight transpose/convert (mode 0/1 segs) + qkv bias gather + tdt.
// Blocks [0,658): segs; [658,665): bias gather; 665: tdt.
// ---------------------------------------------------------------------------
struct WtSeg { const float* src; ushort_t* dst; int K, N, tK, tile0, dstStride, mode; };
struct WtTable { WtSeg s[10]; };

__global__ __launch_bounds__(256) void wt_transpose(
    WtTable tab, const float* __restrict__ qb, const float* __restrict__ kb,
    const float* __restrict__ vb, float* __restrict__ bias_dst,
    const float* __restrict__ dt, const float* __restrict__ yyw,
    const float* __restrict__ yyb, float* __restrict__ tdt_ws,
    float* __restrict__ out_tail)
{
    const int bid = blockIdx.x;
    const int tid = threadIdx.x;
    if (bid == 665) {
        for (int t = tid; t < 512; t += 256) {
            int b = t >> 7, o = t & 127;
            float s = yyb[o];
            for (int k = 0; k < 128; ++k)
                s = fmaf(dt[b * 128 + k], yyw[k * 128 + o], s);
            tdt_ws[t] = s;
            out_tail[t] = s;
        }
        return;
    }
    if (bid >= 658) {
        int t = (bid - 658) * 256 + tid;
        if (t < 520) bias_dst[t] = qb[t];
        else if (t < 1032) bias_dst[t] = kb[t - 520];
        else if (t < 1544) bias_dst[t] = vb[t - 1032];
        return;
    }
    int si = 0;
#pragma unroll
    for (int i = 1; i < 10; ++i)
        if (bid >= tab.s[i].tile0) si = i;
    const WtSeg sg = tab.s[si];
    const int local = bid - sg.tile0;

    if (sg.mode == 1) {
        long base = (long)local * 16384;
#pragma unroll
        for (int i = 0; i < 8; ++i) {
            long p = base + i * 2048 + tid * 8;
            float4 a = *(const float4*)&sg.src[p];
            float4 b = *(const float4*)&sg.src[p + 4];
            bf16x8 o;
            o[0] = (short)f2bf(a.x); o[1] = (short)f2bf(a.y);
            o[2] = (short)f2bf(a.z); o[3] = (short)f2bf(a.w);
            o[4] = (short)f2bf(b.x); o[5] = (short)f2bf(b.y);
            o[6] = (short)f2bf(b.z); o[7] = (short)f2bf(b.w);
            *(bf16x8*)&sg.dst[p] = o;
        }
        return;
    }

    __shared__ float t[64][65];
    const int k0 = (local % sg.tK) * 64;
    const int n0 = (local / sg.tK) * 64;
#pragma unroll
    for (int i = 0; i < 16; ++i) {
        int e = tid + i * 256;
        int r = e >> 6, c = e & 63;
        float v = 0.f;
        if (k0 + r < sg.K && n0 + c < sg.N)
            v = sg.src[(long)(k0 + r) * sg.N + n0 + c];
        t[r][c] = v;
    }
    __syncthreads();
#pragma unroll
    for (int i = 0; i < 16; ++i) {
        int e = tid + i * 256;
        int rn = e >> 6, ck = e & 63;
        if (n0 + rn < sg.N && k0 + ck < sg.K)
            sg.dst[(long)(n0 + rn) * sg.dstStride + k0 + ck] = f2bf(t[ck][rn]);
    }
}

// ---------------------------------------------------------------------------
// Prep2 fat kernel (512 thr): blocks 0-3 wprime-GEMM, 4-19 wohe-GEMM,
// 20-532 biasfold (8 waves/block). Tiny GEMMs overlap with biasfold.
// ---------------------------------------------------------------------------
__global__ __launch_bounds__(512) void prep2_kernel(
    const ushort_t* __restrict__ catwt, const ushort_t* __restrict__ hewt,
    const ushort_t* __restrict__ w2raw, const ushort_t* __restrict__ o_raw,
    ushort_t* __restrict__ wprime, ushort_t* __restrict__ wohe,
    const float* __restrict__ expr_b2, const float* __restrict__ tdt,
    const float* __restrict__ cat_b, const float* __restrict__ o_b,
    const float* __restrict__ he_b, const float* __restrict__ o_w,
    const float* __restrict__ hp_w, const float* __restrict__ hp_b,
    float* __restrict__ bias_h, float* __restrict__ bias_eo,
    float* __restrict__ whp, float* __restrict__ bias_po)
{
    __shared__ __align__(16) ushort_t ls[32768];
    const int bid = blockIdx.x;
    const int tid = threadIdx.x;

    if (bid < 4) {
        // W'[:, :64] = (expr_w2 @ cat_w0)^T rows : grid (1,4)
        hgemm_body<0, 1, 0, 0>(catwt, 768, w2raw, 512, nullptr, wprime, 192,
                               64, 512, 0, bid, ls, ls + 16384);
        return;
    }
    if (bid < 20) {
        // wohe[n][k] = sum_i he_w[i][n] * o_w[k][i] : grid (4,4)
        int local = bid - 4;
        hgemm_body<0, 1, 0, 0>(hewt, 512, o_raw, 512, nullptr, wohe, 512,
                               512, 512, local & 3, local >> 2, ls, ls + 16384);
        return;
    }

    const int wid = (bid - 20) * 8 + (tid >> 6);
    const int lane = tid & 63;
    float s = 0.f;
    if (wid < 2048) {
        int b = wid >> 9, n = wid & 511;
        bf16x8 wv = *(const bf16x8*)&catwt[(long)n * 768 + lane * 8];
        float4 e0 = *(const float4*)&expr_b2[lane * 8];
        float4 e1 = *(const float4*)&expr_b2[lane * 8 + 4];
        s = bf2f((ushort_t)wv[0]) * e0.x + bf2f((ushort_t)wv[1]) * e0.y +
            bf2f((ushort_t)wv[2]) * e0.z + bf2f((ushort_t)wv[3]) * e0.w +
            bf2f((ushort_t)wv[4]) * e1.x + bf2f((ushort_t)wv[5]) * e1.y +
            bf2f((ushort_t)wv[6]) * e1.z + bf2f((ushort_t)wv[7]) * e1.w;
        float2 tt = *(const float2*)&tdt[b * 128 + lane * 2];
        s += bf2f(catwt[(long)n * 768 + 512 + lane * 2]) * tt.x;
        s += bf2f(catwt[(long)n * 768 + 513 + lane * 2]) * tt.y;
#pragma unroll
        for (int o = 32; o >= 1; o >>= 1) s += __shfl_xor(s, o);
        if (lane == 0) bias_h[b * 512 + n] = s + cat_b[n];
    } else if (wid < 2560) {
        int n = wid - 2048;
        bf16x8 wv = *(const bf16x8*)&hewt[(long)n * 512 + lane * 8];
        float4 e0 = *(const float4*)&o_b[lane * 8];
        float4 e1 = *(const float4*)&o_b[lane * 8 + 4];
        s = bf2f((ushort_t)wv[0]) * e0.x + bf2f((ushort_t)wv[1]) * e0.y +
            bf2f((ushort_t)wv[2]) * e0.z + bf2f((ushort_t)wv[3]) * e0.w +
            bf2f((ushort_t)wv[4]) * e1.x + bf2f((ushort_t)wv[5]) * e1.y +
            bf2f((ushort_t)wv[6]) * e1.z + bf2f((ushort_t)wv[7]) * e1.w;
#pragma unroll
        for (int o = 32; o >= 1; o >>= 1) s += __shfl_xor(s, o);
        if (lane == 0) bias_eo[n] = s + he_b[n];
    } else if (wid < 4096) {
        int t = wid - 2560;
        int c = t >> 9, k = t & 511;
#pragma unroll
        for (int i = 0; i < 8; ++i) {
            int j = i * 64 + lane;
            s = fmaf(o_w[(long)k * 512 + j], hp_w[j * 3 + c], s);
        }
#pragma unroll
        for (int o = 32; o >= 1; o >>= 1) s += __shfl_xor(s, o);
        if (lane == 0) whp[k * 3 + c] = s;
    } else if (wid < 4099) {
        int c = wid - 4096;
#pragma unroll
        for (int i = 0; i < 8; ++i) {
            int j = i * 64 + lane;
            s = fmaf(o_b[j], hp_w[j * 3 + c], s);
        }
#pragma unroll
        for (int o = 32; o >= 1; o >>= 1) s += __shfl_xor(s, o);
        if (lane == 0) bias_po[c] = s + hp_b[c];
    }
}

// ---------------------------------------------------------------------------
// MLP fat kernel (512 thr): blocks 0-63 expr-GEMM (grid(1,64)),
// blocks 64-191 posmlp (64 rows/block, 8 threads/row).
// ---------------------------------------------------------------------------
__global__ __launch_bounds__(512) void mlp_kernel(
    const ushort_t* __restrict__ expr_bf, const ushort_t* __restrict__ w1t,
    const float* __restrict__ expr_b1,
    const float* __restrict__ pos,
    const float* __restrict__ w1, const float* __restrict__ b1,
    const float* __restrict__ w2, const float* __restrict__ b2,
    ushort_t* __restrict__ a192)
{
    __shared__ __align__(16) ushort_t ls[32768];
    const int bid = blockIdx.x;
    const int tid = threadIdx.x;

    if (bid < 64) {
        hgemm_body<1, 1, 1, 0>(expr_bf, 512, w1t, 512, expr_b1, a192, 192,
                               64, 512, 0, bid, ls, ls + 16384);
        return;
    }

    // posmlp: w2t stored [128][72] (8-bank spread; 2-way aliasing free)
    float* w1s = (float*)ls;            // 256
    float* b1s = w1s + 256;             // 64
    float* b2s = b1s + 64;              // 128
    float* w2t = b2s + 128;             // 128*72
    if (tid < 256) w1s[tid] = w1[tid];
    if (tid >= 256 && tid < 320) b1s[tid - 256] = b1[tid - 256];
    if (tid >= 320 && tid < 448) b2s[tid - 320] = b2[tid - 320];
    for (int i = tid; i < 8192; i += 512) {
        int k = i >> 7, o = i & 127;
        w2t[o * 72 + k] = w2[i];
    }
    __syncthreads();

    const long r = (long)(bid - 64) * 64 + (tid >> 3);
    const int chunk = tid & 7;
    float px = pos[r * 3 + 0], py = pos[r * 3 + 1], pz = pos[r * 3 + 2];
    float nrm = sqrtf(px * px + py * py + pz * pz);
    float inv = 1.f / (nrm + 1e-7f);
    float pf0 = px * inv, pf1 = py * inv, pf2 = pz * inv, pf3 = nrm;

    float h1[64];
#pragma unroll
    for (int o = 0; o < 64; ++o) {
        float a = b1s[o];
        a = fmaf(pf0, w1s[o], a);
        a = fmaf(pf1, w1s[64 + o], a);
        a = fmaf(pf2, w1s[128 + o], a);
        a = fmaf(pf3, w1s[192 + o], a);
        h1[o] = fmaxf(a, 0.f);
    }
    ushort_t* dst = &a192[r * 192 + 64];
#pragma unroll
    for (int j = 0; j < 16; ++j) {
        int o = chunk + 8 * j;
        float s = b2s[o];
#pragma unroll
        for (int i4 = 0; i4 < 16; ++i4) {
            float4 wv = *(const float4*)&w2t[o * 72 + i4 * 4];
            s = fmaf(h1[i4 * 4 + 0], wv.x, s);
            s = fmaf(h1[i4 * 4 + 1], wv.y, s);
            s = fmaf(h1[i4 * 4 + 2], wv.z, s);
            s = fmaf(h1[i4 * 4 + 3], wv.w, s);
        }
        dst[o] = f2bf(s);
    }
}

// ---------------------------------------------------------------------------
// qkv postprocess: K rmsnorm + V transpose — unchanged.
// ---------------------------------------------------------------------------
__global__ __launch_bounds__(256) void qkvpost_kernel(
    const ushort_t* __restrict__ qkv, const float* __restrict__ knw,
    ushort_t* __restrict__ kn, ushort_t* __restrict__ Vt)
{
    __shared__ ushort_t t[64][72];
    __shared__ float knw_s[64];
    const int bh = blockIdx.x, b = bh >> 3, h = bh & 7;
    const int n0 = blockIdx.y * 64;
    const int tid = threadIdx.x;
    if (tid < 64) knw_s[tid] = knw[tid];
#pragma unroll
    for (int i = 0; i < 2; ++i) {
        int c = tid + i * 256;
        int r = c >> 3, ch = c & 7;
        *(bf16x8*)&t[r][ch * 8] =
            *(const bf16x8*)&qkv[(long)(b * SEQ + n0 + r) * 1544 + 1032 + h * 64 + ch * 8];
    }
    __syncthreads();
#pragma unroll
    for (int i = 0; i < 2; ++i) {
        int c = tid + i * 256;
        int r = c >> 3, ch = c & 7;
        bf16x8 kv = *(const bf16x8*)&qkv[(long)(b * SEQ + n0 + r) * 1544 + 520 + h * 64 + ch * 8];
        float x[8], ss = 0.f;
#pragma unroll
        for (int j = 0; j < 8; ++j) { x[j] = bf2f((ushort_t)kv[j]); ss = fmaf(x[j], x[j], ss); }
        ss += __shfl_xor(ss, 1);
        ss += __shfl_xor(ss, 2);
        ss += __shfl_xor(ss, 4);
        float invr = rsqrtf(ss * (1.f / 64.f) + 1e-6f);
        bf16x8 o;
#pragma unroll
        for (int j = 0; j < 8; ++j) o[j] = (short)f2bf(x[j] * knw_s[ch * 8 + j] * invr);
        *(bf16x8*)&kn[(long)(b * SEQ + n0 + r) * 512 + h * 64 + ch * 8] = o;
    }
    const int d = tid >> 2;
#pragma unroll
    for (int i = 0; i < 2; ++i) {
        int cc = (tid & 3) * 2 + i;
        bf16x8 pk;
#pragma unroll
        for (int j = 0; j < 8; ++j) pk[j] = (short)t[cc * 8 + j][d];
        *(bf16x8*)&Vt[((long)(bh * 64 + d)) * SEQ + n0 + cc * 8] = pk;
    }
}

// ---------------------------------------------------------------------------
// Flash attention — round-10/12 measured-good config, unchanged.
// ---------------------------------------------------------------------------
__global__ __launch_bounds__(256) void flash_attn_mfma(
    const ushort_t* __restrict__ QKV, const ushort_t* __restrict__ Kn,
    const ushort_t* __restrict__ Vt, const float* __restrict__ qnw,
    ushort_t* __restrict__ AO)
{
    __shared__ __align__(16) ushort_t Ks[2][64 * 64];
    __shared__ __align__(16) ushort_t Vs[2][64 * 64];
    __shared__ __align__(16) ushort_t Ps[4][32 * 64];

    const int tid = threadIdx.x;
    const int lane = tid & 63;
    const int w = tid >> 6;
    const int lo = lane & 15, hi = lane >> 4;
    const int bh = blockIdx.x, b = bh >> 3, h = bh & 7;
    const int qb = blockIdx.y * 128 + w * 32;

    bf16x8 qfrag[2][2];
    {
        float qw[2][8];
#pragma unroll
        for (int ks = 0; ks < 2; ++ks)
#pragma unroll
            for (int j = 0; j < 8; ++j)
                qw[ks][j] = qnw[ks * 32 + hi * 8 + j];
#pragma unroll
        for (int jt = 0; jt < 2; ++jt) {
            float qx[2][8], ss = 0.f;
#pragma unroll
            for (int ks = 0; ks < 2; ++ks) {
                bf16x8 q = *(const bf16x8*)&QKV[(long)(b * SEQ + qb + jt * 16 + lo) * 1544 +
                                                h * 64 + ks * 32 + hi * 8];
#pragma unroll
                for (int j = 0; j < 8; ++j) {
                    qx[ks][j] = bf2f((ushort_t)q[j]);
                    ss = fmaf(qx[ks][j], qx[ks][j], ss);
                }
            }
            ss += __shfl_xor(ss, 16);
            ss += __shfl_xor(ss, 32);
            float invr = rsqrtf(ss * (1.f / 64.f) + 1e-6f) * (0.125f * LOG2E);
#pragma unroll
            for (int ks = 0; ks < 2; ++ks) {
                bf16x8 f;
#pragma unroll
                for (int j = 0; j < 8; ++j)
                    f[j] = (short)f2bf(qx[ks][j] * qw[ks][j] * invr);
                qfrag[jt][ks] = f;
            }
        }
    }

    f32x4 accO[2][4];
#pragma unroll
    for (int mt = 0; mt < 2; ++mt)
#pragma unroll
        for (int nt = 0; nt < 4; ++nt) accO[mt][nt] = (f32x4)0.f;
    float l_part[2] = {0.f, 0.f};

    const int sr0 = tid >> 3, sc0 = tid & 7;
    const int sr1 = (tid + 256) >> 3, sc1 = tid & 7;
    const int wo0 = sr0 * 64 + ((sc0 ^ (sr0 & 7)) * 8);
    const int wo1 = sr1 * 64 + ((sc1 ^ (sr1 & 7)) * 8);

    bf16x8 kreg0, kreg1, vreg0, vreg1;
    kreg0 = *(const bf16x8*)&Kn[(b * SEQ + sr0) * 512 + h * 64 + sc0 * 8];
    vreg0 = *(const bf16x8*)&Vt[((long)(bh * 64 + sr0)) * SEQ + sc0 * 8];
    kreg1 = *(const bf16x8*)&Kn[(b * SEQ + sr1) * 512 + h * 64 + sc1 * 8];
    vreg1 = *(const bf16x8*)&Vt[((long)(bh * 64 + sr1)) * SEQ + sc1 * 8];
    *(bf16x8*)&Ks[0][wo0] = kreg0;
    *(bf16x8*)&Vs[0][wo0] = vreg0;
    *(bf16x8*)&Ks[0][wo1] = kreg1;
    *(bf16x8*)&Vs[0][wo1] = vreg1;
    kreg0 = *(const bf16x8*)&Kn[(b * SEQ + 64 + sr0) * 512 + h * 64 + sc0 * 8];
    vreg0 = *(const bf16x8*)&Vt[((long)(bh * 64 + sr0)) * SEQ + 64 + sc0 * 8];
    kreg1 = *(const bf16x8*)&Kn[(b * SEQ + 64 + sr1) * 512 + h * 64 + sc1 * 8];
    vreg1 = *(const bf16x8*)&Vt[((long)(bh * 64 + sr1)) * SEQ + 64 + sc1 * 8];
    __syncthreads();

    auto step = [&](int kt, int cur, int nxt) {
        if (kt + 1 < 32) {
            *(bf16x8*)&Ks[nxt][wo0] = kreg0;
            *(bf16x8*)&Vs[nxt][wo0] = vreg0;
            *(bf16x8*)&Ks[nxt][wo1] = kreg1;
            *(bf16x8*)&Vs[nxt][wo1] = vreg1;
        }
        if (kt + 2 < 32) {
            int nk = (kt + 2) * 64;
            kreg0 = *(const bf16x8*)&Kn[(b * SEQ + nk + sr0) * 512 + h * 64 + sc0 * 8];
            vreg0 = *(const bf16x8*)&Vt[((long)(bh * 64 + sr0)) * SEQ + nk + sc0 * 8];
            kreg1 = *(const bf16x8*)&Kn[(b * SEQ + nk + sr1) * 512 + h * 64 + sc1 * 8];
            vreg1 = *(const bf16x8*)&Vt[((long)(bh * 64 + sr1)) * SEQ + nk + sc1 * 8];
        }

        f32x4 accS[4][2];
#pragma unroll
        for (int it = 0; it < 4; ++it)
#pragma unroll
            for (int jt = 0; jt < 2; ++jt) accS[it][jt] = (f32x4)0.f;

#pragma unroll
        for (int it = 0; it < 4; ++it) {
            bf16x8 kf[2];
#pragma unroll
            for (int ks = 0; ks < 2; ++ks)
                kf[ks] = *(const bf16x8*)&Ks[cur][(it * 16 + lo) * 64 +
                                                 (((ks * 4 + hi) ^ (lo & 7)) * 8)];
#pragma unroll
            for (int jt = 0; jt < 2; ++jt)
#pragma unroll
                for (int ks = 0; ks < 2; ++ks)
                    accS[it][jt] = __builtin_amdgcn_mfma_f32_16x16x32_bf16(
                        kf[ks], qfrag[jt][ks], accS[it][jt], 0, 0, 0);
        }

#pragma unroll
        for (int it = 0; it < 4; ++it)
#pragma unroll
            for (int jt = 0; jt < 2; ++jt) {
                float p0, p1, p2, p3;
                asm("v_exp_f32 %0, %1" : "=v"(p0) : "v"(accS[it][jt][0]));
                asm("v_exp_f32 %0, %1" : "=v"(p1) : "v"(accS[it][jt][1]));
                asm("v_exp_f32 %0, %1" : "=v"(p2) : "v"(accS[it][jt][2]));
                asm("v_exp_f32 %0, %1" : "=v"(p3) : "v"(accS[it][jt][3]));
                l_part[jt] += (p0 + p1) + (p2 + p3);
                unsigned w0, w1;
                asm("v_cvt_pk_bf16_f32 %0, %1, %2" : "=v"(w0) : "v"(p0), "v"(p1));
                asm("v_cvt_pk_bf16_f32 %0, %1, %2" : "=v"(w1) : "v"(p2), "v"(p3));
                int q = jt * 16 + lo;
                int cch = it * 2 + (hi >> 1);
                int off = q * 64 + ((cch ^ (q & 7)) * 8) + (hi & 1) * 4;
                uint2 t; t.x = w0; t.y = w1;
                *(uint2*)&Ps[w][off] = t;
            }

#pragma unroll
        for (int kk = 0; kk < 2; ++kk) {
            bf16x8 pf[2];
#pragma unroll
            for (int mt = 0; mt < 2; ++mt)
                pf[mt] = *(const bf16x8*)&Ps[w][(mt * 16 + lo) * 64 +
                                               (((kk * 4 + hi) ^ (lo & 7)) * 8)];
#pragma unroll
            for (int nt = 0; nt < 4; ++nt) {
                bf16x8 vf = *(const bf16x8*)&Vs[cur][(nt * 16 + lo) * 64 +
                                                    (((kk * 4 + hi) ^ (lo & 7)) * 8)];
#pragma unroll
                for (int mt = 0; mt < 2; ++mt)
                    accO[mt][nt] = __builtin_amdgcn_mfma_f32_16x16x32_bf16(
                        pf[mt], vf, accO[mt][nt], 0, 0, 0);
            }
        }
        __syncthreads();
    };

    for (int kt = 0; kt < 32; kt += 2) {
        step(kt, 0, 1);
        step(kt + 1, 1, 0);
    }

#pragma unroll
    for (int jt = 0; jt < 2; ++jt) {
        l_part[jt] += __shfl_xor(l_part[jt], 16);
        l_part[jt] += __shfl_xor(l_part[jt], 32);
    }

#pragma unroll
    for (int mt = 0; mt < 2; ++mt)
#pragma unroll
        for (int r = 0; r < 4; ++r) {
            float lq = __shfl(l_part[mt], hi * 4 + r);
            int grow = b * SEQ + qb + mt * 16 + hi * 4 + r;
            float g = bf2f(QKV[(long)grow * 1544 + 512 + h]);
            g = 1.f / (1.f + __expf(-g));
            float sc = g / lq;
#pragma unroll
            for (int nt = 0; nt < 4; ++nt)
                AO[(long)grow * 512 + h * 64 + nt * 16 + lo] = f2bf(accO[mt][nt][r] * sc);
        }
}

// ---------------------------------------------------------------------------
// OUT fat kernel (512 thr): blocks 0-255 eo-GEMM (grid(4,64)),
// blocks 256-1279 posout (8 rows/block, one wave per row).
// ---------------------------------------------------------------------------
__global__ __launch_bounds__(512) void out_kernel(
    const ushort_t* __restrict__ ao, const ushort_t* __restrict__ wohe,
    const float* __restrict__ bias_eo, float* __restrict__ eo,
    const float* __restrict__ whp, const float* __restrict__ bpo,
    float* __restrict__ po)
{
    __shared__ __align__(16) ushort_t ls[32768];
    const int bid = blockIdx.x;
    const int tid = threadIdx.x;

    if (bid < 256) {
        hgemm_body<0, 0, 1, 0>(ao, 512, wohe, 512, bias_eo, eo, 512,
                               512, 512, bid & 3, bid >> 2, ls, ls + 16384);
        return;
    }

    const int lane = tid & 63;
    const long row = (long)(bid - 256) * 8 + (tid >> 6);
    float p0 = 0.f, p1 = 0.f, p2 = 0.f;
#pragma unroll
    for (int it = 0; it < 8; ++it) {
        int k = it * 64 + lane;
        float x = bf2f(ao[row * 512 + k]);
        p0 = fmaf(x, whp[k * 3 + 0], p0);
        p1 = fmaf(x, whp[k * 3 + 1], p1);
        p2 = fmaf(x, whp[k * 3 + 2], p2);
    }
#pragma unroll
    for (int o = 32; o >= 1; o >>= 1) {
        p0 += __shfl_xor(p0, o);
        p1 += __shfl_xor(p1, o);
        p2 += __shfl_xor(p2, o);
    }
    if (lane == 0) {
        po[row * 3 + 0] = p0 + bpo[0];
        po[row * 3 + 1] = p1 + bpo[1];
        po[row * 3 + 2] = p2 + bpo[2];
    }
}

// ---------------------------------------------------------------------------
extern "C" void kernel_launch(void* const* d_in, const int* in_sizes, int n_in,
                              void* d_out, int out_size, void* d_ws, size_t ws_size,
                              hipStream_t stream)
{
    const float* expr    = (const float*)d_in[0];
    const float* dtime   = (const float*)d_in[1];
    const float* posf    = (const float*)d_in[2];
    const float* pos_w1  = (const float*)d_in[3];
    const float* pos_b1  = (const float*)d_in[4];
    const float* pos_w2  = (const float*)d_in[5];
    const float* pos_b2  = (const float*)d_in[6];
    const float* expr_w1 = (const float*)d_in[7];
    const float* expr_b1 = (const float*)d_in[8];
    const float* expr_w2 = (const float*)d_in[9];
    const float* expr_b2 = (const float*)d_in[10];
    const float* yy_w    = (const float*)d_in[11];
    const float* yy_b    = (const float*)d_in[12];
    const float* cat_w   = (const float*)d_in[13];
    const float* cat_b   = (const float*)d_in[14];
    const float* q_w     = (const float*)d_in[15];
    const float* q_b     = (const float*)d_in[16];
    const float* k_w     = (const float*)d_in[17];
    const float* k_b     = (const float*)d_in[18];
    const float* v_w     = (const float*)d_in[19];
    const float* v_b     = (const float*)d_in[20];
    const float* o_w     = (const float*)d_in[21];
    const float* o_b     = (const float*)d_in[22];
    const float* qn_w    = (const float*)d_in[23];
    const float* kn_w    = (const float*)d_in[24];
    const float* hp_w    = (const float*)d_in[25];
    const float* hp_b    = (const float*)d_in[26];
    const float* he_w    = (const float*)d_in[27];
    const float* he_b    = (const float*)d_in[28];
    (void)in_sizes; (void)n_in; (void)out_size; (void)ws_size;

    ushort_t* wsb     = (ushort_t*)d_ws;
    ushort_t* expr_bf = wsb + U_EXPR;
    ushort_t* a192    = wsb + U_A192;
    ushort_t* h_bf    = wsb + U_H;
    ushort_t* qkv_bf  = wsb + U_QKV;
    ushort_t* kn_bf   = wsb + U_KN;
    ushort_t* vt_bf   = wsb + U_VT;
    ushort_t* ao_bf   = wsb + U_AO;
    ushort_t* w1t     = wsb + U_W1T;
    ushort_t* w2raw   = wsb + U_W2RAW;
    ushort_t* cat_wt  = wsb + U_CATWT;
    ushort_t* qkv_wt  = wsb + U_QKVWT;
    ushort_t* he_wt   = wsb + U_HEWT;
    ushort_t* wprime  = wsb + U_WPRIME;
    ushort_t* wohe    = wsb + U_WOHE;
    ushort_t* o_raw   = wsb + U_ORAW;
    float* f32r       = (float*)(wsb + U_F32);
    float* tdt        = f32r + F_TDT;
    float* qkv_bias   = f32r + F_QKVB;
    float* bias_h     = f32r + F_BIASH;
    float* bias_eo    = f32r + F_BIASEO;
    float* bias_po    = f32r + F_BIASPO;
    float* whp        = f32r + F_WHP;
    float* dout       = (float*)d_out;

    const dim3 blk(256);
    const dim3 blk512(512);

    // --- prep1: all converts/transposes + bias gather + tdt ---
    WtTable tab;
    //            src              dst               K    N   tK tile0 dstS mode
    tab.s[0] = { expr_w1,          w1t,             512,  64,  8,   0, 512, 0 };  //   8
    tab.s[1] = { cat_w,            cat_wt,          768, 512, 12,   8, 768, 0 };  //  96
    tab.s[2] = { q_w,              qkv_wt,          512, 520,  8, 104, 512, 0 };  //  72
    tab.s[3] = { k_w,              qkv_wt + 520*512,512, 512,  8, 176, 512, 0 };  //  64
    tab.s[4] = { v_w,              qkv_wt +1032*512,512, 512,  8, 240, 512, 0 };  //  64
    tab.s[5] = { he_w,             he_wt,           512, 512,  8, 304, 512, 0 };  //  64
    tab.s[6] = { cat_w + 640*512,  wprime + 64,     128, 512,  2, 368, 192, 0 };  //  16
    tab.s[7] = { expr_w2,          w2raw,             0,   0,  0, 384,   0, 1 };  //   2
    tab.s[8] = { o_w,              o_raw,             0,   0,  0, 386,   0, 1 };  //  16
    tab.s[9] = { expr,             expr_bf,           0,   0,  0, 402,   0, 1 };  // 256 -> 658
    wt_transpose<<<dim3(666), blk, 0, stream>>>(tab, q_b, k_b, v_b, qkv_bias,
                                                dtime, yy_w, yy_b, tdt,
                                                dout + DOUT_TDT);

    // --- prep2: wprime-GEMM + wohe-GEMM + biasfold, concurrent ---
    prep2_kernel<<<dim3(533), blk512, 0, stream>>>(
        cat_wt, he_wt, w2raw, o_raw, wprime, wohe,
        expr_b2, tdt, cat_b, o_b, he_b, o_w, hp_w, hp_b,
        bias_h, bias_eo, whp, bias_po);

    // --- pipeline ---
    // a192 = [relu(expr@w1+b1) | posMLP]  (expr-GEMM + posmlp concurrent)
    mlp_kernel<<<dim3(192), blk512, 0, stream>>>(
        expr_bf, w1t, expr_b1, posf, pos_w1, pos_b1, pos_w2, pos_b2, a192);
    // h = a192 @ W'^T + bias_h[batch]
    hgemm<0, 1, 1, 512><<<dim3(4, 64), blk512, 0, stream>>>(a192, 192, wprime, 192,
                                                            bias_h, h_bf, 512, 512, 192);
    // qkv = h @ [q|k|v] + bias
    hgemm<0, 1, 1, 0><<<dim3(13, 64), blk512, 0, stream>>>(h_bf, 512, qkv_wt, 512,
                                                           qkv_bias, qkv_bf, 1544, 1544, 512);
    qkvpost_kernel<<<dim3(32, 32), blk, 0, stream>>>(qkv_bf, kn_w, kn_bf, vt_bf);
    flash_attn_mfma<<<dim3(32, 16), blk, 0, stream>>>(qkv_bf, kn_bf, vt_bf, qn_w, ao_bf);
    // expr_out (eo-GEMM) + pos_out, concurrent
    out_kernel<<<dim3(1280), blk512, 0, stream>>>(
        ao_bf, wohe, bias_eo, dout + DOUT_EXPR, whp, bias_po, dout + DOUT_POS);
}

// Round 14
// 124.321 us; speedup vs baseline: 1.4135x; 1.0874x over previous
//
#include <hip/hip_runtime.h>
#include <math.h>

// Problem constants
#define SEQ   2048
#define NROWS 8192   // B*N

typedef unsigned short ushort_t;
typedef __attribute__((ext_vector_type(8))) short bf16x8;
typedef __attribute__((ext_vector_type(4))) float f32x4;

// Workspace offsets (ushort units)
#define U_EXPR   0ull            // 8192*512
#define U_A192   4194304ull      // 8192*192  ([te1|tp])
#define U_H      5767168ull      // 8192*512
#define U_QKV    9961472ull      // 8192*1544
#define U_KN     26804224ull     // 8192*512
#define U_VT     30998528ull     // 32*64*2048
#define U_AO     35192832ull     // 8192*512
#define U_W1T    39387136ull     // 64*512
#define U_W2RAW  39419904ull     // 64*512
#define U_CATWT  39452672ull     // 512*768
#define U_QKVWT  39845888ull     // 1544*512
#define U_HEWT   40898560ull     // 512*512
#define U_WPRIME 41160704ull     // 512*192
#define U_WOHE   41259008ull     // 512*512
#define U_F32    41521152ull     // fp32 region (8192 floats)
#define U_ORAW   41537536ull     // 512*512 bf16, o_w native layout

// fp32 region layout (float offsets)
#define F_TDT    0
#define F_QKVB   512
#define F_BIASH  2056    // [4][512]
#define F_BIASEO 4104    // [512]
#define F_BIASPO 4616    // [4]
#define F_WHP    4620    // [512][3]

// d_out offsets (floats): (expr_out, pos_out, tdt)
#define DOUT_EXPR 0ull
#define DOUT_POS  4194304ull
#define DOUT_TDT  4218880ull

#define LOG2E 1.44269504088896340736f

static __device__ __forceinline__ ushort_t f2bf(float f) {
    union { float f; unsigned int u; } v; v.f = f;
    unsigned int r = (v.u + 0x7fffu + ((v.u >> 16) & 1u)) >> 16;
    return (ushort_t)r;
}
static __device__ __forceinline__ float bf2f(ushort_t u) {
    union { unsigned int u; float f; } v; v.u = ((unsigned int)u) << 16;
    return v.f;
}

// async global->LDS, 16B per lane; LDS dest = wave-uniform base + lane*16
static __device__ __forceinline__ void gload16(const void* g, void* l) {
    __builtin_amdgcn_global_load_lds(
        (const __attribute__((address_space(1))) void*)g,
        (__attribute__((address_space(3))) void*)l,
        16, 0, 0);
}

// ---------------------------------------------------------------------------
// hgemm body (device fn): C[128M x 128N tile] = A @ Wt^T + bias.
// Compile-time K (KC) -> fully unrolled K-loop. Double-buffered LDS
// (64KB from caller), global_load_lds staging (swizzled source), one
// barrier per K-step. 512 threads.
// ---------------------------------------------------------------------------
template <int RELU, int OUT_BF16, int HASBIAS, int BBSTRIDE, int KC>
static __device__ void hgemm_body(
    const ushort_t* __restrict__ A, int lda,
    const ushort_t* __restrict__ Wt, int ldw,
    const float* __restrict__ bias,
    void* __restrict__ Cv, int ldc,
    int N, int bx, int by,
    ushort_t* AsB, ushort_t* BsB)
{
    const int tid = threadIdx.x;
    const int lane = tid & 63, w = tid >> 6;
    const int lo = lane & 15, hi = lane >> 4;
    const int wm = w >> 2, wn = w & 3;
    const long m0 = (long)by * 128;
    const int n0 = bx * 128;

    f32x4 acc[4][2];
#pragma unroll
    for (int mt = 0; mt < 4; ++mt)
#pragma unroll
        for (int nt = 0; nt < 2; ++nt) acc[mt][nt] = (f32x4)0.f;

    auto stage = [&](int kt, int buf) {
#pragma unroll
        for (int i = 0; i < 2; ++i) {
            int c = w * 128 + i * 64 + lane;
            int r = c >> 3, ch = c & 7;
            int sch = ch ^ (r & 7);
            gload16(&A[(m0 + r) * (long)lda + kt + sch * 8],
                    &AsB[buf * 8192 + (w * 128 + i * 64) * 8]);
            gload16(&Wt[(long)(n0 + r) * ldw + kt + sch * 8],
                    &BsB[buf * 8192 + (w * 128 + i * 64) * 8]);
        }
    };

    stage(0, 0);
    __syncthreads();

#pragma unroll
    for (int step = 0; step < KC / 64; ++step) {
        const int cur = step & 1;
        if ((step + 1) * 64 < KC) stage((step + 1) * 64, cur ^ 1);

#pragma unroll
        for (int ks = 0; ks < 2; ++ks) {
            bf16x8 af[4], bfr[2];
#pragma unroll
            for (int mt = 0; mt < 4; ++mt) {
                int m = wm * 64 + mt * 16 + lo;
                af[mt] = *(const bf16x8*)&AsB[cur * 8192 + m * 64 +
                                              (((ks * 4 + hi) ^ (lo & 7)) * 8)];
            }
#pragma unroll
            for (int nt = 0; nt < 2; ++nt) {
                int n = wn * 32 + nt * 16 + lo;
                bfr[nt] = *(const bf16x8*)&BsB[cur * 8192 + n * 64 +
                                               (((ks * 4 + hi) ^ (lo & 7)) * 8)];
            }
#pragma unroll
            for (int mt = 0; mt < 4; ++mt)
#pragma unroll
                for (int nt = 0; nt < 2; ++nt)
                    acc[mt][nt] = __builtin_amdgcn_mfma_f32_16x16x32_bf16(
                        af[mt], bfr[nt], acc[mt][nt], 0, 0, 0);
        }
        __syncthreads();
    }

#pragma unroll
    for (int mt = 0; mt < 4; ++mt)
#pragma unroll
        for (int nt = 0; nt < 2; ++nt) {
            int col = n0 + wn * 32 + nt * 16 + lo;
            if (col < N) {
                float bv = 0.f;
                if (HASBIAS)
                    bv = BBSTRIDE ? bias[(int)(m0 >> 11) * BBSTRIDE + col] : bias[col];
#pragma unroll
                for (int r = 0; r < 4; ++r) {
                    long row = m0 + wm * 64 + mt * 16 + hi * 4 + r;
                    float v = acc[mt][nt][r] + bv;
                    if (RELU) v = fmaxf(v, 0.f);
                    if (OUT_BF16) ((ushort_t*)Cv)[row * (long)ldc + col] = f2bf(v);
                    else          ((float*)Cv)[row * (long)ldc + col] = v;
                }
            }
        }
}

// Standalone hgemm: 1-D grid (nwg % 8 == 0), XCD-chunked bijective swizzle
// so consecutive tiles (sharing A-panels) land on one XCD's L2.
template <int RELU, int OUT_BF16, int HASBIAS, int BBSTRIDE, int KC>
__global__ __launch_bounds__(512) void hgemm(
    const ushort_t* __restrict__ A, int lda,
    const ushort_t* __restrict__ Wt, int ldw,
    const float* __restrict__ bias,
    void* __restrict__ Cv, int ldc, int N, int gx)
{
    __shared__ __align__(16) ushort_t ls[32768];
    const int nwg = gridDim.x;
    const int bid = blockIdx.x;
    const int cpx = nwg >> 3;
    const int swz = (bid & 7) * cpx + (bid >> 3);   // nwg % 8 == 0
    hgemm_body<RELU, OUT_BF16, HASBIAS, BBSTRIDE, KC>(
        A, lda, Wt, ldw, bias, Cv, ldc, N,
        swz % gx, swz / gx, ls, ls + 16384);
}

// ---------------------------------------------------------------------------
// Prep1: weight transpose/convert (mode 0/1 segs) + qkv bias gather + tdt.
// Blocks [0,658): segs; [658,665): bias gather; 665: tdt.
// ---------------------------------------------------------------------------
struct WtSeg { const float* src; ushort_t* dst; int K, N, tK, tile0, dstStride, mode; };
struct WtTable { WtSeg s[10]; };

__global__ __launch_bounds__(256) void wt_transpose(
    WtTable tab, const float* __restrict__ qb, const float* __restrict__ kb,
    const float* __restrict__ vb, float* __restrict__ bias_dst,
    const float* __restrict__ dt, const float* __restrict__ yyw,
    const float* __restrict__ yyb, float* __restrict__ tdt_ws,
    float* __restrict__ out_tail)
{
    const int bid = blockIdx.x;
    const int tid = threadIdx.x;
    if (bid == 665) {
        for (int t = tid; t < 512; t += 256) {
            int b = t >> 7, o = t & 127;
            float s = yyb[o];
            for (int k = 0; k < 128; ++k)
                s = fmaf(dt[b * 128 + k], yyw[k * 128 + o], s);
            tdt_ws[t] = s;
            out_tail[t] = s;
        }
        return;
    }
    if (bid >= 658) {
        int t = (bid - 658) * 256 + tid;
        if (t < 520) bias_dst[t] = qb[t];
        else if (t < 1032) bias_dst[t] = kb[t - 520];
        else if (t < 1544) bias_dst[t] = vb[t - 1032];
        return;
    }
    int si = 0;
#pragma unroll
    for (int i = 1; i < 10; ++i)
        if (bid >= tab.s[i].tile0) si = i;
    const WtSeg sg = tab.s[si];
    const int local = bid - sg.tile0;

    if (sg.mode == 1) {
        long base = (long)local * 16384;
#pragma unroll
        for (int i = 0; i < 8; ++i) {
            long p = base + i * 2048 + tid * 8;
            float4 a = *(const float4*)&sg.src[p];
            float4 b = *(const float4*)&sg.src[p + 4];
            bf16x8 o;
            o[0] = (short)f2bf(a.x); o[1] = (short)f2bf(a.y);
            o[2] = (short)f2bf(a.z); o[3] = (short)f2bf(a.w);
            o[4] = (short)f2bf(b.x); o[5] = (short)f2bf(b.y);
            o[6] = (short)f2bf(b.z); o[7] = (short)f2bf(b.w);
            *(bf16x8*)&sg.dst[p] = o;
        }
        return;
    }

    __shared__ float t[64][65];
    const int k0 = (local % sg.tK) * 64;
    const int n0 = (local / sg.tK) * 64;
#pragma unroll
    for (int i = 0; i < 16; ++i) {
        int e = tid + i * 256;
        int r = e >> 6, c = e & 63;
        float v = 0.f;
        if (k0 + r < sg.K && n0 + c < sg.N)
            v = sg.src[(long)(k0 + r) * sg.N + n0 + c];
        t[r][c] = v;
    }
    __syncthreads();
#pragma unroll
    for (int i = 0; i < 16; ++i) {
        int e = tid + i * 256;
        int rn = e >> 6, ck = e & 63;
        if (n0 + rn < sg.N && k0 + ck < sg.K)
            sg.dst[(long)(n0 + rn) * sg.dstStride + k0 + ck] = f2bf(t[ck][rn]);
    }
}

// ---------------------------------------------------------------------------
// Prep2+MLP fat kernel (512 thr): 0-3 wprime-GEMM, 4-19 wohe-GEMM,
// 20-532 biasfold, 533-596 expr-GEMM, 597-724 posmlp. All independent
// given prep1; tiny GEMMs overlap with biasfold/posmlp occupancy.
// ---------------------------------------------------------------------------
__global__ __launch_bounds__(512) void prep2mlp_kernel(
    const ushort_t* __restrict__ catwt, const ushort_t* __restrict__ hewt,
    const ushort_t* __restrict__ w2raw, const ushort_t* __restrict__ o_raw,
    ushort_t* __restrict__ wprime, ushort_t* __restrict__ wohe,
    const float* __restrict__ expr_b2, const float* __restrict__ tdt,
    const float* __restrict__ cat_b, const float* __restrict__ o_b,
    const float* __restrict__ he_b, const float* __restrict__ o_w,
    const float* __restrict__ hp_w, const float* __restrict__ hp_b,
    float* __restrict__ bias_h, float* __restrict__ bias_eo,
    float* __restrict__ whp, float* __restrict__ bias_po,
    const ushort_t* __restrict__ expr_bf, const ushort_t* __restrict__ w1t,
    const float* __restrict__ expr_b1,
    const float* __restrict__ pos,
    const float* __restrict__ w1, const float* __restrict__ b1,
    const float* __restrict__ w2, const float* __restrict__ b2,
    ushort_t* __restrict__ a192)
{
    __shared__ __align__(16) ushort_t ls[32768];
    const int bid = blockIdx.x;
    const int tid = threadIdx.x;

    if (bid < 4) {
        hgemm_body<0, 1, 0, 0, 512>(catwt, 768, w2raw, 512, nullptr, wprime, 192,
                                    64, 0, bid, ls, ls + 16384);
        return;
    }
    if (bid < 20) {
        int local = bid - 4;
        hgemm_body<0, 1, 0, 0, 512>(hewt, 512, o_raw, 512, nullptr, wohe, 512,
                                    512, local & 3, local >> 2, ls, ls + 16384);
        return;
    }
    if (bid < 533) {
        const int wid = (bid - 20) * 8 + (tid >> 6);
        const int lane = tid & 63;
        float s = 0.f;
        if (wid < 2048) {
            int b = wid >> 9, n = wid & 511;
            bf16x8 wv = *(const bf16x8*)&catwt[(long)n * 768 + lane * 8];
            float4 e0 = *(const float4*)&expr_b2[lane * 8];
            float4 e1 = *(const float4*)&expr_b2[lane * 8 + 4];
            s = bf2f((ushort_t)wv[0]) * e0.x + bf2f((ushort_t)wv[1]) * e0.y +
                bf2f((ushort_t)wv[2]) * e0.z + bf2f((ushort_t)wv[3]) * e0.w +
                bf2f((ushort_t)wv[4]) * e1.x + bf2f((ushort_t)wv[5]) * e1.y +
                bf2f((ushort_t)wv[6]) * e1.z + bf2f((ushort_t)wv[7]) * e1.w;
            float2 tt = *(const float2*)&tdt[b * 128 + lane * 2];
            s += bf2f(catwt[(long)n * 768 + 512 + lane * 2]) * tt.x;
            s += bf2f(catwt[(long)n * 768 + 513 + lane * 2]) * tt.y;
#pragma unroll
            for (int o = 32; o >= 1; o >>= 1) s += __shfl_xor(s, o);
            if (lane == 0) bias_h[b * 512 + n] = s + cat_b[n];
        } else if (wid < 2560) {
            int n = wid - 2048;
            bf16x8 wv = *(const bf16x8*)&hewt[(long)n * 512 + lane * 8];
            float4 e0 = *(const float4*)&o_b[lane * 8];
            float4 e1 = *(const float4*)&o_b[lane * 8 + 4];
            s = bf2f((ushort_t)wv[0]) * e0.x + bf2f((ushort_t)wv[1]) * e0.y +
                bf2f((ushort_t)wv[2]) * e0.z + bf2f((ushort_t)wv[3]) * e0.w +
                bf2f((ushort_t)wv[4]) * e1.x + bf2f((ushort_t)wv[5]) * e1.y +
                bf2f((ushort_t)wv[6]) * e1.z + bf2f((ushort_t)wv[7]) * e1.w;
#pragma unroll
            for (int o = 32; o >= 1; o >>= 1) s += __shfl_xor(s, o);
            if (lane == 0) bias_eo[n] = s + he_b[n];
        } else if (wid < 4096) {
            int t = wid - 2560;
            int c = t >> 9, k = t & 511;
#pragma unroll
            for (int i = 0; i < 8; ++i) {
                int j = i * 64 + lane;
                s = fmaf(o_w[(long)k * 512 + j], hp_w[j * 3 + c], s);
            }
#pragma unroll
            for (int o = 32; o >= 1; o >>= 1) s += __shfl_xor(s, o);
            if (lane == 0) whp[k * 3 + c] = s;
        } else if (wid < 4099) {
            int c = wid - 4096;
#pragma unroll
            for (int i = 0; i < 8; ++i) {
                int j = i * 64 + lane;
                s = fmaf(o_b[j], hp_w[j * 3 + c], s);
            }
#pragma unroll
            for (int o = 32; o >= 1; o >>= 1) s += __shfl_xor(s, o);
            if (lane == 0) bias_po[c] = s + hp_b[c];
        }
        return;
    }
    if (bid < 597) {
        hgemm_body<1, 1, 1, 0, 512>(expr_bf, 512, w1t, 512, expr_b1, a192, 192,
                                    64, 0, bid - 533, ls, ls + 16384);
        return;
    }

    // posmlp: w2t stored [128][72] (8-bank spread; 2-way aliasing free)
    float* w1s = (float*)ls;            // 256
    float* b1s = w1s + 256;             // 64
    float* b2s = b1s + 64;              // 128
    float* w2t = b2s + 128;             // 128*72
    if (tid < 256) w1s[tid] = w1[tid];
    if (tid >= 256 && tid < 320) b1s[tid - 256] = b1[tid - 256];
    if (tid >= 320 && tid < 448) b2s[tid - 320] = b2[tid - 320];
    for (int i = tid; i < 8192; i += 512) {
        int k = i >> 7, o = i & 127;
        w2t[o * 72 + k] = w2[i];
    }
    __syncthreads();

    const long r = (long)(bid - 597) * 64 + (tid >> 3);
    const int chunk = tid & 7;
    float px = pos[r * 3 + 0], py = pos[r * 3 + 1], pz = pos[r * 3 + 2];
    float nrm = sqrtf(px * px + py * py + pz * pz);
    float inv = 1.f / (nrm + 1e-7f);
    float pf0 = px * inv, pf1 = py * inv, pf2 = pz * inv, pf3 = nrm;

    float h1[64];
#pragma unroll
    for (int o = 0; o < 64; ++o) {
        float a = b1s[o];
        a = fmaf(pf0, w1s[o], a);
        a = fmaf(pf1, w1s[64 + o], a);
        a = fmaf(pf2, w1s[128 + o], a);
        a = fmaf(pf3, w1s[192 + o], a);
        h1[o] = fmaxf(a, 0.f);
    }
    ushort_t* dst = &a192[r * 192 + 64];
#pragma unroll
    for (int j = 0; j < 16; ++j) {
        int o = chunk + 8 * j;
        float s = b2s[o];
#pragma unroll
        for (int i4 = 0; i4 < 16; ++i4) {
            float4 wv = *(const float4*)&w2t[o * 72 + i4 * 4];
            s = fmaf(h1[i4 * 4 + 0], wv.x, s);
            s = fmaf(h1[i4 * 4 + 1], wv.y, s);
            s = fmaf(h1[i4 * 4 + 2], wv.z, s);
            s = fmaf(h1[i4 * 4 + 3], wv.w, s);
        }
        dst[o] = f2bf(s);
    }
}

// ---------------------------------------------------------------------------
// qkv postprocess: K rmsnorm + V transpose — unchanged.
// ---------------------------------------------------------------------------
__global__ __launch_bounds__(256) void qkvpost_kernel(
    const ushort_t* __restrict__ qkv, const float* __restrict__ knw,
    ushort_t* __restrict__ kn, ushort_t* __restrict__ Vt)
{
    __shared__ ushort_t t[64][72];
    __shared__ float knw_s[64];
    const int bh = blockIdx.x, b = bh >> 3, h = bh & 7;
    const int n0 = blockIdx.y * 64;
    const int tid = threadIdx.x;
    if (tid < 64) knw_s[tid] = knw[tid];
#pragma unroll
    for (int i = 0; i < 2; ++i) {
        int c = tid + i * 256;
        int r = c >> 3, ch = c & 7;
        *(bf16x8*)&t[r][ch * 8] =
            *(const bf16x8*)&qkv[(long)(b * SEQ + n0 + r) * 1544 + 1032 + h * 64 + ch * 8];
    }
    __syncthreads();
#pragma unroll
    for (int i = 0; i < 2; ++i) {
        int c = tid + i * 256;
        int r = c >> 3, ch = c & 7;
        bf16x8 kv = *(const bf16x8*)&qkv[(long)(b * SEQ + n0 + r) * 1544 + 520 + h * 64 + ch * 8];
        float x[8], ss = 0.f;
#pragma unroll
        for (int j = 0; j < 8; ++j) { x[j] = bf2f((ushort_t)kv[j]); ss = fmaf(x[j], x[j], ss); }
        ss += __shfl_xor(ss, 1);
        ss += __shfl_xor(ss, 2);
        ss += __shfl_xor(ss, 4);
        float invr = rsqrtf(ss * (1.f / 64.f) + 1e-6f);
        bf16x8 o;
#pragma unroll
        for (int j = 0; j < 8; ++j) o[j] = (short)f2bf(x[j] * knw_s[ch * 8 + j] * invr);
        *(bf16x8*)&kn[(long)(b * SEQ + n0 + r) * 512 + h * 64 + ch * 8] = o;
    }
    const int d = tid >> 2;
#pragma unroll
    for (int i = 0; i < 2; ++i) {
        int cc = (tid & 3) * 2 + i;
        bf16x8 pk;
#pragma unroll
        for (int j = 0; j < 8; ++j) pk[j] = (short)t[cc * 8 + j][d];
        *(bf16x8*)&Vt[((long)(bh * 64 + d)) * SEQ + n0 + cc * 8] = pk;
    }
}

// ---------------------------------------------------------------------------
// Flash attention — measured-good config (r10/r12/r13), unchanged.
// ---------------------------------------------------------------------------
__global__ __launch_bounds__(256) void flash_attn_mfma(
    const ushort_t* __restrict__ QKV, const ushort_t* __restrict__ Kn,
    const ushort_t* __restrict__ Vt, const float* __restrict__ qnw,
    ushort_t* __restrict__ AO)
{
    __shared__ __align__(16) ushort_t Ks[2][64 * 64];
    __shared__ __align__(16) ushort_t Vs[2][64 * 64];
    __shared__ __align__(16) ushort_t Ps[4][32 * 64];

    const int tid = threadIdx.x;
    const int lane = tid & 63;
    const int w = tid >> 6;
    const int lo = lane & 15, hi = lane >> 4;
    const int bh = blockIdx.x, b = bh >> 3, h = bh & 7;
    const int qb = blockIdx.y * 128 + w * 32;

    bf16x8 qfrag[2][2];
    {
        float qw[2][8];
#pragma unroll
        for (int ks = 0; ks < 2; ++ks)
#pragma unroll
            for (int j = 0; j < 8; ++j)
                qw[ks][j] = qnw[ks * 32 + hi * 8 + j];
#pragma unroll
        for (int jt = 0; jt < 2; ++jt) {
            float qx[2][8], ss = 0.f;
#pragma unroll
            for (int ks = 0; ks < 2; ++ks) {
                bf16x8 q = *(const bf16x8*)&QKV[(long)(b * SEQ + qb + jt * 16 + lo) * 1544 +
                                                h * 64 + ks * 32 + hi * 8];
#pragma unroll
                for (int j = 0; j < 8; ++j) {
                    qx[ks][j] = bf2f((ushort_t)q[j]);
                    ss = fmaf(qx[ks][j], qx[ks][j], ss);
                }
            }
            ss += __shfl_xor(ss, 16);
            ss += __shfl_xor(ss, 32);
            float invr = rsqrtf(ss * (1.f / 64.f) + 1e-6f) * (0.125f * LOG2E);
#pragma unroll
            for (int ks = 0; ks < 2; ++ks) {
                bf16x8 f;
#pragma unroll
                for (int j = 0; j < 8; ++j)
                    f[j] = (short)f2bf(qx[ks][j] * qw[ks][j] * invr);
                qfrag[jt][ks] = f;
            }
        }
    }

    f32x4 accO[2][4];
#pragma unroll
    for (int mt = 0; mt < 2; ++mt)
#pragma unroll
        for (int nt = 0; nt < 4; ++nt) accO[mt][nt] = (f32x4)0.f;
    float l_part[2] = {0.f, 0.f};

    const int sr0 = tid >> 3, sc0 = tid & 7;
    const int sr1 = (tid + 256) >> 3, sc1 = tid & 7;
    const int wo0 = sr0 * 64 + ((sc0 ^ (sr0 & 7)) * 8);
    const int wo1 = sr1 * 64 + ((sc1 ^ (sr1 & 7)) * 8);

    bf16x8 kreg0, kreg1, vreg0, vreg1;
    kreg0 = *(const bf16x8*)&Kn[(b * SEQ + sr0) * 512 + h * 64 + sc0 * 8];
    vreg0 = *(const bf16x8*)&Vt[((long)(bh * 64 + sr0)) * SEQ + sc0 * 8];
    kreg1 = *(const bf16x8*)&Kn[(b * SEQ + sr1) * 512 + h * 64 + sc1 * 8];
    vreg1 = *(const bf16x8*)&Vt[((long)(bh * 64 + sr1)) * SEQ + sc1 * 8];
    *(bf16x8*)&Ks[0][wo0] = kreg0;
    *(bf16x8*)&Vs[0][wo0] = vreg0;
    *(bf16x8*)&Ks[0][wo1] = kreg1;
    *(bf16x8*)&Vs[0][wo1] = vreg1;
    kreg0 = *(const bf16x8*)&Kn[(b * SEQ + 64 + sr0) * 512 + h * 64 + sc0 * 8];
    vreg0 = *(const bf16x8*)&Vt[((long)(bh * 64 + sr0)) * SEQ + 64 + sc0 * 8];
    kreg1 = *(const bf16x8*)&Kn[(b * SEQ + 64 + sr1) * 512 + h * 64 + sc1 * 8];
    vreg1 = *(const bf16x8*)&Vt[((long)(bh * 64 + sr1)) * SEQ + 64 + sc1 * 8];
    __syncthreads();

    auto step = [&](int kt, int cur, int nxt) {
        if (kt + 1 < 32) {
            *(bf16x8*)&Ks[nxt][wo0] = kreg0;
            *(bf16x8*)&Vs[nxt][wo0] = vreg0;
            *(bf16x8*)&Ks[nxt][wo1] = kreg1;
            *(bf16x8*)&Vs[nxt][wo1] = vreg1;
        }
        if (kt + 2 < 32) {
            int nk = (kt + 2) * 64;
            kreg0 = *(const bf16x8*)&Kn[(b * SEQ + nk + sr0) * 512 + h * 64 + sc0 * 8];
            vreg0 = *(const bf16x8*)&Vt[((long)(bh * 64 + sr0)) * SEQ + nk + sc0 * 8];
            kreg1 = *(const bf16x8*)&Kn[(b * SEQ + nk + sr1) * 512 + h * 64 + sc1 * 8];
            vreg1 = *(const bf16x8*)&Vt[((long)(bh * 64 + sr1)) * SEQ + nk + sc1 * 8];
        }

        f32x4 accS[4][2];
#pragma unroll
        for (int it = 0; it < 4; ++it)
#pragma unroll
            for (int jt = 0; jt < 2; ++jt) accS[it][jt] = (f32x4)0.f;

#pragma unroll
        for (int it = 0; it < 4; ++it) {
            bf16x8 kf[2];
#pragma unroll
            for (int ks = 0; ks < 2; ++ks)
                kf[ks] = *(const bf16x8*)&Ks[cur][(it * 16 + lo) * 64 +
                                                 (((ks * 4 + hi) ^ (lo & 7)) * 8)];
#pragma unroll
            for (int jt = 0; jt < 2; ++jt)
#pragma unroll
                for (int ks = 0; ks < 2; ++ks)
                    accS[it][jt] = __builtin_amdgcn_mfma_f32_16x16x32_bf16(
                        kf[ks], qfrag[jt][ks], accS[it][jt], 0, 0, 0);
        }

#pragma unroll
        for (int it = 0; it < 4; ++it)
#pragma unroll
            for (int jt = 0; jt < 2; ++jt) {
                float p0, p1, p2, p3;
                asm("v_exp_f32 %0, %1" : "=v"(p0) : "v"(accS[it][jt][0]));
                asm("v_exp_f32 %0, %1" : "=v"(p1) : "v"(accS[it][jt][1]));
                asm("v_exp_f32 %0, %1" : "=v"(p2) : "v"(accS[it][jt][2]));
                asm("v_exp_f32 %0, %1" : "=v"(p3) : "v"(accS[it][jt][3]));
                l_part[jt] += (p0 + p1) + (p2 + p3);
                unsigned w0, w1;
                asm("v_cvt_pk_bf16_f32 %0, %1, %2" : "=v"(w0) : "v"(p0), "v"(p1));
                asm("v_cvt_pk_bf16_f32 %0, %1, %2" : "=v"(w1) : "v"(p2), "v"(p3));
                int q = jt * 16 + lo;
                int cch = it * 2 + (hi >> 1);
                int off = q * 64 + ((cch ^ (q & 7)) * 8) + (hi & 1) * 4;
                uint2 t; t.x = w0; t.y = w1;
                *(uint2*)&Ps[w][off] = t;
            }

#pragma unroll
        for (int kk = 0; kk < 2; ++kk) {
            bf16x8 pf[2];
#pragma unroll
            for (int mt = 0; mt < 2; ++mt)
                pf[mt] = *(const bf16x8*)&Ps[w][(mt * 16 + lo) * 64 +
                                               (((kk * 4 + hi) ^ (lo & 7)) * 8)];
#pragma unroll
            for (int nt = 0; nt < 4; ++nt) {
                bf16x8 vf = *(const bf16x8*)&Vs[cur][(nt * 16 + lo) * 64 +
                                                    (((kk * 4 + hi) ^ (lo & 7)) * 8)];
#pragma unroll
                for (int mt = 0; mt < 2; ++mt)
                    accO[mt][nt] = __builtin_amdgcn_mfma_f32_16x16x32_bf16(
                        pf[mt], vf, accO[mt][nt], 0, 0, 0);
            }
        }
        __syncthreads();
    };

    for (int kt = 0; kt < 32; kt += 2) {
        step(kt, 0, 1);
        step(kt + 1, 1, 0);
    }

#pragma unroll
    for (int jt = 0; jt < 2; ++jt) {
        l_part[jt] += __shfl_xor(l_part[jt], 16);
        l_part[jt] += __shfl_xor(l_part[jt], 32);
    }

#pragma unroll
    for (int mt = 0; mt < 2; ++mt)
#pragma unroll
        for (int r = 0; r < 4; ++r) {
            float lq = __shfl(l_part[mt], hi * 4 + r);
            int grow = b * SEQ + qb + mt * 16 + hi * 4 + r;
            float g = bf2f(QKV[(long)grow * 1544 + 512 + h]);
            g = 1.f / (1.f + __expf(-g));
            float sc = g / lq;
#pragma unroll
            for (int nt = 0; nt < 4; ++nt)
                AO[(long)grow * 512 + h * 64 + nt * 16 + lo] = f2bf(accO[mt][nt][r] * sc);
        }
}

// ---------------------------------------------------------------------------
// OUT fat kernel (512 thr): blocks 0-255 eo-GEMM (grid(4,64)),
// blocks 256-1279 posout (8 rows/block, one wave per row).
// ---------------------------------------------------------------------------
__global__ __launch_bounds__(512) void out_kernel(
    const ushort_t* __restrict__ ao, const ushort_t* __restrict__ wohe,
    const float* __restrict__ bias_eo, float* __restrict__ eo,
    const float* __restrict__ whp, const float* __restrict__ bpo,
    float* __restrict__ po)
{
    __shared__ __align__(16) ushort_t ls[32768];
    const int bid = blockIdx.x;
    const int tid = threadIdx.x;

    if (bid < 256) {
        hgemm_body<0, 0, 1, 0, 512>(ao, 512, wohe, 512, bias_eo, eo, 512,
                                    512, bid & 3, bid >> 2, ls, ls + 16384);
        return;
    }

    const int lane = tid & 63;
    const long row = (long)(bid - 256) * 8 + (tid >> 6);
    float p0 = 0.f, p1 = 0.f, p2 = 0.f;
#pragma unroll
    for (int it = 0; it < 8; ++it) {
        int k = it * 64 + lane;
        float x = bf2f(ao[row * 512 + k]);
        p0 = fmaf(x, whp[k * 3 + 0], p0);
        p1 = fmaf(x, whp[k * 3 + 1], p1);
        p2 = fmaf(x, whp[k * 3 + 2], p2);
    }
#pragma unroll
    for (int o = 32; o >= 1; o >>= 1) {
        p0 += __shfl_xor(p0, o);
        p1 += __shfl_xor(p1, o);
        p2 += __shfl_xor(p2, o);
    }
    if (lane == 0) {
        po[row * 3 + 0] = p0 + bpo[0];
        po[row * 3 + 1] = p1 + bpo[1];
        po[row * 3 + 2] = p2 + bpo[2];
    }
}

// ---------------------------------------------------------------------------
extern "C" void kernel_launch(void* const* d_in, const int* in_sizes, int n_in,
                              void* d_out, int out_size, void* d_ws, size_t ws_size,
                              hipStream_t stream)
{
    const float* expr    = (const float*)d_in[0];
    const float* dtime   = (const float*)d_in[1];
    const float* posf    = (const float*)d_in[2];
    const float* pos_w1  = (const float*)d_in[3];
    const float* pos_b1  = (const float*)d_in[4];
    const float* pos_w2  = (const float*)d_in[5];
    const float* pos_b2  = (const float*)d_in[6];
    const float* expr_w1 = (const float*)d_in[7];
    const float* expr_b1 = (const float*)d_in[8];
    const float* expr_w2 = (const float*)d_in[9];
    const float* expr_b2 = (const float*)d_in[10];
    const float* yy_w    = (const float*)d_in[11];
    const float* yy_b    = (const float*)d_in[12];
    const float* cat_w   = (const float*)d_in[13];
    const float* cat_b   = (const float*)d_in[14];
    const float* q_w     = (const float*)d_in[15];
    const float* q_b     = (const float*)d_in[16];
    const float* k_w     = (const float*)d_in[17];
    const float* k_b     = (const float*)d_in[18];
    const float* v_w     = (const float*)d_in[19];
    const float* v_b     = (const float*)d_in[20];
    const float* o_w     = (const float*)d_in[21];
    const float* o_b     = (const float*)d_in[22];
    const float* qn_w    = (const float*)d_in[23];
    const float* kn_w    = (const float*)d_in[24];
    const float* hp_w    = (const float*)d_in[25];
    const float* hp_b    = (const float*)d_in[26];
    const float* he_w    = (const float*)d_in[27];
    const float* he_b    = (const float*)d_in[28];
    (void)in_sizes; (void)n_in; (void)out_size; (void)ws_size;

    ushort_t* wsb     = (ushort_t*)d_ws;
    ushort_t* expr_bf = wsb + U_EXPR;
    ushort_t* a192    = wsb + U_A192;
    ushort_t* h_bf    = wsb + U_H;
    ushort_t* qkv_bf  = wsb + U_QKV;
    ushort_t* kn_bf   = wsb + U_KN;
    ushort_t* vt_bf   = wsb + U_VT;
    ushort_t* ao_bf   = wsb + U_AO;
    ushort_t* w1t     = wsb + U_W1T;
    ushort_t* w2raw   = wsb + U_W2RAW;
    ushort_t* cat_wt  = wsb + U_CATWT;
    ushort_t* qkv_wt  = wsb + U_QKVWT;
    ushort_t* he_wt   = wsb + U_HEWT;
    ushort_t* wprime  = wsb + U_WPRIME;
    ushort_t* wohe    = wsb + U_WOHE;
    ushort_t* o_raw   = wsb + U_ORAW;
    float* f32r       = (float*)(wsb + U_F32);
    float* tdt        = f32r + F_TDT;
    float* qkv_bias   = f32r + F_QKVB;
    float* bias_h     = f32r + F_BIASH;
    float* bias_eo    = f32r + F_BIASEO;
    float* bias_po    = f32r + F_BIASPO;
    float* whp        = f32r + F_WHP;
    float* dout       = (float*)d_out;

    const dim3 blk(256);
    const dim3 blk512(512);

    // --- prep1: converts/transposes + bias gather + tdt ---
    WtTable tab;
    //            src              dst               K    N   tK tile0 dstS mode
    tab.s[0] = { expr_w1,          w1t,             512,  64,  8,   0, 512, 0 };  //   8
    tab.s[1] = { cat_w,            cat_wt,          768, 512, 12,   8, 768, 0 };  //  96
    tab.s[2] = { q_w,              qkv_wt,          512, 520,  8, 104, 512, 0 };  //  72
    tab.s[3] = { k_w,              qkv_wt + 520*512,512, 512,  8, 176, 512, 0 };  //  64
    tab.s[4] = { v_w,              qkv_wt +1032*512,512, 512,  8, 240, 512, 0 };  //  64
    tab.s[5] = { he_w,             he_wt,           512, 512,  8, 304, 512, 0 };  //  64
    tab.s[6] = { cat_w + 640*512,  wprime + 64,     128, 512,  2, 368, 192, 0 };  //  16
    tab.s[7] = { expr_w2,          w2raw,             0,   0,  0, 384,   0, 1 };  //   2
    tab.s[8] = { o_w,              o_raw,             0,   0,  0, 386,   0, 1 };  //  16
    tab.s[9] = { expr,             expr_bf,           0,   0,  0, 402,   0, 1 };  // 256 -> 658
    wt_transpose<<<dim3(666), blk, 0, stream>>>(tab, q_b, k_b, v_b, qkv_bias,
                                                dtime, yy_w, yy_b, tdt,
                                                dout + DOUT_TDT);

    // --- prep2 + mlp, all concurrent ---
    prep2mlp_kernel<<<dim3(725), blk512, 0, stream>>>(
        cat_wt, he_wt, w2raw, o_raw, wprime, wohe,
        expr_b2, tdt, cat_b, o_b, he_b, o_w, hp_w, hp_b,
        bias_h, bias_eo, whp, bias_po,
        expr_bf, w1t, expr_b1, posf, pos_w1, pos_b1, pos_w2, pos_b2, a192);

    // --- pipeline ---
    // h = a192 @ W'^T + bias_h[batch]  (grid 256, XCD swizzle)
    hgemm<0, 1, 1, 512, 192><<<dim3(256), blk512, 0, stream>>>(
        a192, 192, wprime, 192, bias_h, h_bf, 512, 512, 4);
    // qkv = h @ [q|k|v] + bias  (grid 832, XCD swizzle)
    hgemm<0, 1, 1, 0, 512><<<dim3(832), blk512, 0, stream>>>(
        h_bf, 512, qkv_wt, 512, qkv_bias, qkv_bf, 1544, 1544, 13);
    qkvpost_kernel<<<dim3(32, 32), blk, 0, stream>>>(qkv_bf, kn_w, kn_bf, vt_bf);
    flash_attn_mfma<<<dim3(32, 16), blk, 0, stream>>>(qkv_bf, kn_bf, vt_bf, qn_w, ao_bf);
    // expr_out (eo-GEMM) + pos_out, concurrent
    out_kernel<<<dim3(1280), blk512, 0, stream>>>(
        ao_bf, wohe, bias_eo, dout + DOUT_EXPR, whp, bias_po, dout + DOUT_POS);
}